// Round 17
// baseline (418.550 us; speedup 1.0000x reference)
//
#include <hip/hip_runtime.h>

// ---------------------------------------------------------------------------
// Pipeline:
//  k_prep : w2[64,32,3] -> w2t[3,32,64]; wfc[512,64] -> wB{h,m,l} bf16
//  kA     : h[v] = mean_j relu(conv3_j(vp[nb1[v,:]]))               [V]
//  kB     : h3[v] = (h[v-1], h[v], h[v+1], 0)                       [V,4]
//  kF     : FUSED kC+kD+kE per 32-vertex block, 512 THREADS / 8 WAVES
//
// R20 = R19 + __launch_bounds__(512,5) on kF. R19 (512-thr parallel ph4)
// hit 362us total / kF 151us -- best -- but RA picked 52 VGPR vs ~70-88
// live/peak -> residual spill (WRITE 241 vs 200MB; reloads L2-absorbed,
// stores leak). Occupancy 41% looks scratch-capped. RA-ledger conclusion:
// the bounds arg is an occupancy TARGET; the untried config is a cap JUST
// ABOVE live: (512,5) -> cap 512/5 ~= 102 >= 88 peak -> RA can hit the
// target withOUT spilling (inverse of R13's cap-64-under-live failure).
// Verify: VGPR -> ~96-102, WRITE -> ~205MB, occ -> ~55-62%, kF ~115-135.
// ---------------------------------------------------------------------------

typedef short bf16x8 __attribute__((ext_vector_type(8)));
typedef float f32x4 __attribute__((ext_vector_type(4)));

__device__ inline unsigned short f2bf(float x) {
    unsigned u = __float_as_uint(x);
    unsigned r = (u + 0x7FFFu + ((u >> 16) & 1u)) >> 16;
    return (unsigned short)r;
}
__device__ inline float bf2f(unsigned short b) {
    return __uint_as_float(((unsigned)b) << 16);
}

// k_prep: w2 transpose + wfc -> 3-way bf16 split in B-fragment order.
__global__ __launch_bounds__(256) void k_prep(const float* __restrict__ wfc,
                                              const float* __restrict__ w2,
                                              short* __restrict__ wBh,
                                              short* __restrict__ wBm,
                                              short* __restrict__ wBl,
                                              float* __restrict__ w2t) {
    int t = blockIdx.x * 256 + threadIdx.x;
    if (t < 32768) {
        int j = t & 7;
        int l = (t >> 3) & 63;
        int s = (t >> 9) & 1;
        int n = t >> 10;
        int col = n * 16 + (l & 15);
        int k = s * 32 + (l >> 4) * 8 + j;
        float v = wfc[col * 64 + k];
        unsigned short h = f2bf(v);
        float r1 = v - bf2f(h);
        unsigned short m = f2bf(r1);
        float r2 = r1 - bf2f(m);
        wBh[t] = (short)h;
        wBm[t] = (short)m;
        wBl[t] = (short)f2bf(r2);
    } else if (t < 32768 + 6144) {
        int i = t - 32768;
        int o = i / 96;
        int r = i - o * 96;
        int c = r / 3;
        int k = r - c * 3;
        w2t[(k * 32 + c) * 64 + o] = w2[i];
    }
}

// conv1 over neighbor axis: one 32-lane segment per vertex
__global__ __launch_bounds__(256) void kA(const float* __restrict__ vp,
                                          const int* __restrict__ nb1,
                                          const float* __restrict__ wv1,
                                          const float* __restrict__ bv1,
                                          float* __restrict__ h, int V) {
    int t = blockIdx.x * 256 + threadIdx.x;
    int v = t >> 5;
    int j = t & 31;
    if (v >= V) return;
    float g = vp[nb1[v * 32 + j]];
    float gm = __shfl_up(g, 1, 32);
    if (j == 0) gm = 0.0f;
    float gp = __shfl_down(g, 1, 32);
    if (j == 31) gp = 0.0f;
    float c = wv1[0] * gm + wv1[1] * g + wv1[2] * gp + bv1[0];
    c = fmaxf(c, 0.0f);
    #pragma unroll
    for (int off = 16; off; off >>= 1) c += __shfl_xor(c, off, 32);
    if (j == 0) h[v] = c * (1.0f / 32.0f);
}

// h3 builder: h3[v] = (h[v-1], h[v], h[v+1], 0) -- 1.6MB, L2-resident
__global__ __launch_bounds__(256) void kB(const float* __restrict__ h,
                                          float* __restrict__ h3, int V) {
    int v = blockIdx.x * 256 + threadIdx.x;
    if (v >= V) return;
    float hm = (v > 0) ? h[v - 1] : 0.0f;
    float h0 = h[v];
    float hp = (v + 1 < V) ? h[v + 1] : 0.0f;
    *(float4*)(h3 + (size_t)v * 4) = make_float4(hm, h0, hp, 0.0f);
}

// FUSED kC+kD+kE. One block = 32 vertices, 512 threads / 8 waves.
// (512,5): VGPR cap ~102 >= ~88 peak live -> no spill, 5 waves/EU.
__global__ __launch_bounds__(512, 5) void kF(const float* __restrict__ h3,
                                             const int* __restrict__ nb2,
                                             const float* __restrict__ w1,
                                             const float* __restrict__ b1,
                                             const float* __restrict__ wv2,
                                             const float* __restrict__ bv2,
                                             const float* __restrict__ w2t,
                                             const float* __restrict__ b2,
                                             const short* __restrict__ wBh,
                                             const short* __restrict__ wBm,
                                             const short* __restrict__ wBl,
                                             const float* __restrict__ bfc,
                                             float* __restrict__ out, int V) {
    __shared__ float h3s[34 * 32 * 4];   // 17408 B; ph3+ aliased as f2s[32][68]
    __shared__ float h2s[34 * 32];       // 4352 B, rows v0-1 .. v0+32
    __shared__ float redmax[8][16];
    __shared__ float redsum[8][16];
    float* f2s = h3s;                    // alias (dead after ph2; barrier-fenced)

    int t = threadIdx.x;
    int vbase = blockIdx.x * 32;

    // ---- ph1: gather h3[nb2[v,j]] for 34 halo rows ----
    for (int i = t; i < 34 * 32; i += 512) {
        int r = i >> 5;                  // tile row, vertex v = vbase-1+r
        int j = i & 31;
        int v = vbase - 1 + r;
        float4 val = make_float4(0.f, 0.f, 0.f, 0.f);
        if (v >= 0 && v < V) {
            int idx = nb2[(size_t)v * 32 + j];
            val = *(const float4*)(h3 + (size_t)idx * 4);
        }
        *(float4*)(h3s + i * 4) = val;
    }
    __syncthreads();

    // ---- ph2: h2[r][c] = mean_j relu(conv3_j(f1_synth)) ----
    for (int i = t; i < 34 * 32; i += 512) {
        int r = i >> 5;
        int c = i & 31;
        int v = vbase - 1 + r;
        float res = 0.0f;
        if (v >= 0 && v < V) {
            float u0 = w1[c * 3 + 0], u1 = w1[c * 3 + 1], u2 = w1[c * 3 + 2];
            float bc = b1[c];
            float w0 = wv2[0], w1_ = wv2[1], w2_ = wv2[2], b = bv2[0];
            const float* base = h3s + r * 32 * 4;
            float4 hh = *(const float4*)(base);
            float xprev = 0.0f;
            float xcur = fmaf(hh.x, u0, fmaf(hh.y, u1, fmaf(hh.z, u2, bc)));
            float s = 0.0f;
            #pragma unroll
            for (int j = 0; j < 32; ++j) {
                float xnext = 0.0f;
                if (j < 31) {
                    float4 hn = *(const float4*)(base + (j + 1) * 4);
                    xnext = fmaf(hn.x, u0, fmaf(hn.y, u1, fmaf(hn.z, u2, bc)));
                }
                float cv = fmaf(w0, xprev, fmaf(w1_, xcur, fmaf(w2_, xnext, b)));
                s += fmaxf(cv, 0.0f);
                xprev = xcur;
                xcur = xnext;
            }
            res = s * (1.0f / 32.0f);
        }
        h2s[r * 32 + c] = res;
    }
    __syncthreads();

    // ---- ph3: kD einsum from h2s -> f2s[32][68] (LDS); 8 waves x 4 rows --
    {
        int o = t & 63;
        int w8 = t >> 6;      // 0..7
        int vb = w8 * 4;
        float bo = b2[o];
        float acc[4];
        #pragma unroll
        for (int m = 0; m < 4; ++m) acc[m] = bo;

        #pragma unroll
        for (int c4 = 0; c4 < 8; ++c4) {
            float4 hv[6];
            #pragma unroll
            for (int r = 0; r < 6; ++r)
                hv[r] = *(const float4*)(h2s + (vb + r) * 32 + c4 * 4);
            #pragma unroll
            for (int k = 0; k < 3; ++k) {
                #pragma unroll
                for (int cc = 0; cc < 4; ++cc) {
                    int c = c4 * 4 + cc;
                    float wv = w2t[(k * 32 + c) * 64 + o];
                    #pragma unroll
                    for (int m = 0; m < 4; ++m) {
                        float hval = (cc == 0) ? hv[m + k].x :
                                     (cc == 1) ? hv[m + k].y :
                                     (cc == 2) ? hv[m + k].z : hv[m + k].w;
                        acc[m] = fmaf(hval, wv, acc[m]);
                    }
                }
            }
        }
        __syncthreads();   // all h3s reads (ph2) complete; safe to alias
        #pragma unroll
        for (int m = 0; m < 4; ++m)
            f2s[(vb + m) * 68 + o] = acc[m];
    }
    __syncthreads();

    // ---- ph4: kE MFMA fc + softmax; wave w8 owns row-set (w8>>2),
    //      N-tiles (w8&3)*8 .. +7. Live state ~70 floats/thread. ----
    int w8 = t >> 6;         // 0..7
    int set = w8 >> 2;       // row-set 0..1
    int wq = w8 & 3;         // N-quadrant 0..3
    int l = t & 63;
    int c16 = l & 15;
    int g = l >> 4;          // K-group / row-group

    bf16x8 ah0, am0, al0, ah1, am1, al1;
#define SPLIT(AH, AM, AL, idx, x) { \
        float xx = (x); \
        unsigned short h_ = f2bf(xx); \
        float r1_ = xx - bf2f(h_); \
        unsigned short m_ = f2bf(r1_); \
        float r2_ = r1_ - bf2f(m_); \
        AH[idx] = (short)h_; AM[idx] = (short)m_; AL[idx] = (short)f2bf(r2_); }
    {
        const float* rowp = f2s + (set * 16 + c16) * 68 + g * 8;
        float4 q0 = *(const float4*)(rowp);        // s=0, k=g*8..+3
        float4 q1 = *(const float4*)(rowp + 4);    // s=0, k=g*8+4..+7
        float4 q2 = *(const float4*)(rowp + 32);   // s=1
        float4 q3 = *(const float4*)(rowp + 36);
        SPLIT(ah0, am0, al0, 0, q0.x) SPLIT(ah0, am0, al0, 1, q0.y)
        SPLIT(ah0, am0, al0, 2, q0.z) SPLIT(ah0, am0, al0, 3, q0.w)
        SPLIT(ah0, am0, al0, 4, q1.x) SPLIT(ah0, am0, al0, 5, q1.y)
        SPLIT(ah0, am0, al0, 6, q1.z) SPLIT(ah0, am0, al0, 7, q1.w)
        SPLIT(ah1, am1, al1, 0, q2.x) SPLIT(ah1, am1, al1, 1, q2.y)
        SPLIT(ah1, am1, al1, 2, q2.z) SPLIT(ah1, am1, al1, 3, q2.w)
        SPLIT(ah1, am1, al1, 4, q3.x) SPLIT(ah1, am1, al1, 5, q3.y)
        SPLIT(ah1, am1, al1, 6, q3.z) SPLIT(ah1, am1, al1, 7, q3.w)
    }
#undef SPLIT

    f32x4 acc[8];
    const bf16x8* Bh = (const bf16x8*)wBh;
    const bf16x8* Bm = (const bf16x8*)wBm;
    const bf16x8* Bl = (const bf16x8*)wBl;
    #pragma unroll
    for (int n8 = 0; n8 < 8; ++n8) {
        int n = wq * 8 + n8;
        bf16x8 bh0 = Bh[(n * 2 + 0) * 64 + l];
        bf16x8 bm0 = Bm[(n * 2 + 0) * 64 + l];
        bf16x8 bl0 = Bl[(n * 2 + 0) * 64 + l];
        bf16x8 bh1 = Bh[(n * 2 + 1) * 64 + l];
        bf16x8 bm1 = Bm[(n * 2 + 1) * 64 + l];
        bf16x8 bl1 = Bl[(n * 2 + 1) * 64 + l];
        float bn = bfc[n * 16 + c16];
        f32x4 c = {0.f, 0.f, 0.f, 0.f};
        c = __builtin_amdgcn_mfma_f32_16x16x32_bf16(ah0, bh0, c, 0, 0, 0);
        c = __builtin_amdgcn_mfma_f32_16x16x32_bf16(ah0, bm0, c, 0, 0, 0);
        c = __builtin_amdgcn_mfma_f32_16x16x32_bf16(am0, bh0, c, 0, 0, 0);
        c = __builtin_amdgcn_mfma_f32_16x16x32_bf16(ah0, bl0, c, 0, 0, 0);
        c = __builtin_amdgcn_mfma_f32_16x16x32_bf16(am0, bm0, c, 0, 0, 0);
        c = __builtin_amdgcn_mfma_f32_16x16x32_bf16(al0, bh0, c, 0, 0, 0);
        c = __builtin_amdgcn_mfma_f32_16x16x32_bf16(ah1, bh1, c, 0, 0, 0);
        c = __builtin_amdgcn_mfma_f32_16x16x32_bf16(ah1, bm1, c, 0, 0, 0);
        c = __builtin_amdgcn_mfma_f32_16x16x32_bf16(am1, bh1, c, 0, 0, 0);
        c = __builtin_amdgcn_mfma_f32_16x16x32_bf16(ah1, bl1, c, 0, 0, 0);
        c = __builtin_amdgcn_mfma_f32_16x16x32_bf16(am1, bm1, c, 0, 0, 0);
        c = __builtin_amdgcn_mfma_f32_16x16x32_bf16(al1, bh1, c, 0, 0, 0);
        c.x += bn; c.y += bn; c.z += bn; c.w += bn;
        acc[n8] = c;
    }

    // ---- softmax: rows set*16 + g*4 + j; 16-lane reduce then 4-wave
    //      combine (waves set*4 .. set*4+3) via LDS ----
    float m0 = -1e30f, m1 = -1e30f, m2 = -1e30f, m3 = -1e30f;
    #pragma unroll
    for (int n8 = 0; n8 < 8; ++n8) {
        m0 = fmaxf(m0, acc[n8].x); m1 = fmaxf(m1, acc[n8].y);
        m2 = fmaxf(m2, acc[n8].z); m3 = fmaxf(m3, acc[n8].w);
    }
    #pragma unroll
    for (int off = 8; off; off >>= 1) {
        m0 = fmaxf(m0, __shfl_xor(m0, off));
        m1 = fmaxf(m1, __shfl_xor(m1, off));
        m2 = fmaxf(m2, __shfl_xor(m2, off));
        m3 = fmaxf(m3, __shfl_xor(m3, off));
    }
    if (c16 == 0) {
        redmax[w8][g * 4 + 0] = m0;  redmax[w8][g * 4 + 1] = m1;
        redmax[w8][g * 4 + 2] = m2;  redmax[w8][g * 4 + 3] = m3;
    }
    __syncthreads();
#define GMAX(r) fmaxf(fmaxf(redmax[set * 4 + 0][r], redmax[set * 4 + 1][r]), \
                      fmaxf(redmax[set * 4 + 2][r], redmax[set * 4 + 3][r]))
    float g0 = GMAX(g * 4 + 0), g1 = GMAX(g * 4 + 1);
    float g2 = GMAX(g * 4 + 2), g3 = GMAX(g * 4 + 3);
#undef GMAX

    float s0 = 0.f, s1 = 0.f, s2 = 0.f, s3 = 0.f;
    #pragma unroll
    for (int n8 = 0; n8 < 8; ++n8) {
        acc[n8].x = __expf(acc[n8].x - g0); s0 += acc[n8].x;
        acc[n8].y = __expf(acc[n8].y - g1); s1 += acc[n8].y;
        acc[n8].z = __expf(acc[n8].z - g2); s2 += acc[n8].z;
        acc[n8].w = __expf(acc[n8].w - g3); s3 += acc[n8].w;
    }
    #pragma unroll
    for (int off = 8; off; off >>= 1) {
        s0 += __shfl_xor(s0, off); s1 += __shfl_xor(s1, off);
        s2 += __shfl_xor(s2, off); s3 += __shfl_xor(s3, off);
    }
    if (c16 == 0) {
        redsum[w8][g * 4 + 0] = s0;  redsum[w8][g * 4 + 1] = s1;
        redsum[w8][g * 4 + 2] = s2;  redsum[w8][g * 4 + 3] = s3;
    }
    __syncthreads();
#define GSUM(r) (redsum[set * 4 + 0][r] + redsum[set * 4 + 1][r] + \
                 redsum[set * 4 + 2][r] + redsum[set * 4 + 3][r])
    float i0 = 1.0f / GSUM(g * 4 + 0), i1 = 1.0f / GSUM(g * 4 + 1);
    float i2 = 1.0f / GSUM(g * 4 + 2), i3 = 1.0f / GSUM(g * 4 + 3);
#undef GSUM

    // ---- store: out[(vbase+set*16+g*4+j)*512 + n*16 + c16] ----
    #pragma unroll
    for (int n8 = 0; n8 < 8; ++n8) {
        int n = wq * 8 + n8;
        float* op = out + (size_t)(vbase + set * 16 + g * 4) * 512 + n * 16 + c16;
        __builtin_nontemporal_store(acc[n8].x * i0, op);
        __builtin_nontemporal_store(acc[n8].y * i1, op + 512);
        __builtin_nontemporal_store(acc[n8].z * i2, op + 1024);
        __builtin_nontemporal_store(acc[n8].w * i3, op + 1536);
    }
}

extern "C" void kernel_launch(void* const* d_in, const int* in_sizes, int n_in,
                              void* d_out, int out_size, void* d_ws, size_t ws_size,
                              hipStream_t stream) {
    (void)n_in; (void)out_size; (void)ws_size;
    const float* vp  = (const float*)d_in[0];
    const int*   nb1 = (const int*)d_in[1];
    const int*   nb2 = (const int*)d_in[2];
    const float* wv1 = (const float*)d_in[3];
    const float* bv1 = (const float*)d_in[4];
    const float* w1  = (const float*)d_in[5];
    const float* b1  = (const float*)d_in[6];
    const float* wv2 = (const float*)d_in[7];
    const float* bv2 = (const float*)d_in[8];
    const float* w2  = (const float*)d_in[9];
    const float* b2  = (const float*)d_in[10];
    const float* wfc = (const float*)d_in[11];
    const float* bfc = (const float*)d_in[12];
    float* out = (float*)d_out;
    const int V = in_sizes[0];

    float* ws = (float*)d_ws;
    size_t off = 0;
    float* h    = ws + off; off += (size_t)V;
    float* h3   = ws + off; off += (size_t)V * 4;   // 16B aligned
    float* w2t  = ws + off; off += 3 * 32 * 64;
    short* wBh  = (short*)(ws + off); off += 32768 / 2;   // 32768 shorts
    short* wBm  = (short*)(ws + off); off += 32768 / 2;
    short* wBl  = (short*)(ws + off); off += 32768 / 2;

    k_prep<<<(32768 + 6144 + 255) / 256, 256, 0, stream>>>(wfc, w2, wBh, wBm, wBl, w2t);
    kA<<<(V * 32 + 255) / 256, 256, 0, stream>>>(vp, nb1, wv1, bv1, h, V);
    kB<<<(V + 255) / 256, 256, 0, stream>>>(h, h3, V);
    kF<<<V / 32, 512, 0, stream>>>(h3, nb2, w1, b1, wv2, bv2, w2t, b2,
                                   wBh, wBm, wBl, bfc, out, V);
}

// Round 18
// 360.134 us; speedup vs baseline: 1.1622x; 1.1622x over previous
//
#include <hip/hip_runtime.h>

// ---------------------------------------------------------------------------
// Pipeline:
//  k_prep : w2[64,32,3] -> w2t[3,32,64]; wfc[512,64] -> wB{h,m,l} bf16
//  kA     : h[v] = mean_j relu(conv3_j(vp[nb1[v,:]]))               [V]
//  kB     : h3[v] = (h[v-1], h[v], h[v+1], 0)                       [V,4]
//  kF     : FUSED kC+kD+kE per 32-vertex block, 512 THREADS / 8 WAVES
//
// R21 = R19 (the 362us best: bare 512-thr) + SPLIT-K ph4.
// Launch-bounds ledger CLOSED: 4/4 attempts (R13/R15/R17 down, R14 up)
// made RA shrink the budget to the occupancy target and spill the diff.
// Remaining R19 cost: RA picks 52 VGPR vs ~88 ph4 peak live -> ~41MB spill.
// Fix structurally: ph4 runs K=0..31 for all 8 N-tiles (live: ah0/am0/al0
// 12 VGPR + acc[8] 32), then K=32..63 (ah1/am1/al1). Per-tile MFMA chain
// order preserved (first-6 then last-6 into same acc) -> BIT-IDENTICAL.
// B-frags re-read per phase (R9: free). Peak live ~88 -> ~64.
// Verify: WRITE 241 -> ~210-220MB, kF 151 -> ~130-140.
// ---------------------------------------------------------------------------

typedef short bf16x8 __attribute__((ext_vector_type(8)));
typedef float f32x4 __attribute__((ext_vector_type(4)));

__device__ inline unsigned short f2bf(float x) {
    unsigned u = __float_as_uint(x);
    unsigned r = (u + 0x7FFFu + ((u >> 16) & 1u)) >> 16;
    return (unsigned short)r;
}
__device__ inline float bf2f(unsigned short b) {
    return __uint_as_float(((unsigned)b) << 16);
}

// k_prep: w2 transpose + wfc -> 3-way bf16 split in B-fragment order.
__global__ __launch_bounds__(256) void k_prep(const float* __restrict__ wfc,
                                              const float* __restrict__ w2,
                                              short* __restrict__ wBh,
                                              short* __restrict__ wBm,
                                              short* __restrict__ wBl,
                                              float* __restrict__ w2t) {
    int t = blockIdx.x * 256 + threadIdx.x;
    if (t < 32768) {
        int j = t & 7;
        int l = (t >> 3) & 63;
        int s = (t >> 9) & 1;
        int n = t >> 10;
        int col = n * 16 + (l & 15);
        int k = s * 32 + (l >> 4) * 8 + j;
        float v = wfc[col * 64 + k];
        unsigned short h = f2bf(v);
        float r1 = v - bf2f(h);
        unsigned short m = f2bf(r1);
        float r2 = r1 - bf2f(m);
        wBh[t] = (short)h;
        wBm[t] = (short)m;
        wBl[t] = (short)f2bf(r2);
    } else if (t < 32768 + 6144) {
        int i = t - 32768;
        int o = i / 96;
        int r = i - o * 96;
        int c = r / 3;
        int k = r - c * 3;
        w2t[(k * 32 + c) * 64 + o] = w2[i];
    }
}

// conv1 over neighbor axis: one 32-lane segment per vertex
__global__ __launch_bounds__(256) void kA(const float* __restrict__ vp,
                                          const int* __restrict__ nb1,
                                          const float* __restrict__ wv1,
                                          const float* __restrict__ bv1,
                                          float* __restrict__ h, int V) {
    int t = blockIdx.x * 256 + threadIdx.x;
    int v = t >> 5;
    int j = t & 31;
    if (v >= V) return;
    float g = vp[nb1[v * 32 + j]];
    float gm = __shfl_up(g, 1, 32);
    if (j == 0) gm = 0.0f;
    float gp = __shfl_down(g, 1, 32);
    if (j == 31) gp = 0.0f;
    float c = wv1[0] * gm + wv1[1] * g + wv1[2] * gp + bv1[0];
    c = fmaxf(c, 0.0f);
    #pragma unroll
    for (int off = 16; off; off >>= 1) c += __shfl_xor(c, off, 32);
    if (j == 0) h[v] = c * (1.0f / 32.0f);
}

// h3 builder: h3[v] = (h[v-1], h[v], h[v+1], 0) -- 1.6MB, L2-resident
__global__ __launch_bounds__(256) void kB(const float* __restrict__ h,
                                          float* __restrict__ h3, int V) {
    int v = blockIdx.x * 256 + threadIdx.x;
    if (v >= V) return;
    float hm = (v > 0) ? h[v - 1] : 0.0f;
    float h0 = h[v];
    float hp = (v + 1 < V) ? h[v + 1] : 0.0f;
    *(float4*)(h3 + (size_t)v * 4) = make_float4(hm, h0, hp, 0.0f);
}

// FUSED kC+kD+kE. One block = 32 vertices, 512 threads / 8 waves.
__global__ __launch_bounds__(512) void kF(const float* __restrict__ h3,
                                          const int* __restrict__ nb2,
                                          const float* __restrict__ w1,
                                          const float* __restrict__ b1,
                                          const float* __restrict__ wv2,
                                          const float* __restrict__ bv2,
                                          const float* __restrict__ w2t,
                                          const float* __restrict__ b2,
                                          const short* __restrict__ wBh,
                                          const short* __restrict__ wBm,
                                          const short* __restrict__ wBl,
                                          const float* __restrict__ bfc,
                                          float* __restrict__ out, int V) {
    __shared__ float h3s[34 * 32 * 4];   // 17408 B; ph3+ aliased as f2s[32][68]
    __shared__ float h2s[34 * 32];       // 4352 B, rows v0-1 .. v0+32
    __shared__ float redmax[8][16];
    __shared__ float redsum[8][16];
    float* f2s = h3s;                    // alias (dead after ph2; barrier-fenced)

    int t = threadIdx.x;
    int vbase = blockIdx.x * 32;

    // ---- ph1: gather h3[nb2[v,j]] for 34 halo rows ----
    for (int i = t; i < 34 * 32; i += 512) {
        int r = i >> 5;                  // tile row, vertex v = vbase-1+r
        int j = i & 31;
        int v = vbase - 1 + r;
        float4 val = make_float4(0.f, 0.f, 0.f, 0.f);
        if (v >= 0 && v < V) {
            int idx = nb2[(size_t)v * 32 + j];
            val = *(const float4*)(h3 + (size_t)idx * 4);
        }
        *(float4*)(h3s + i * 4) = val;
    }
    __syncthreads();

    // ---- ph2: h2[r][c] = mean_j relu(conv3_j(f1_synth)) ----
    for (int i = t; i < 34 * 32; i += 512) {
        int r = i >> 5;
        int c = i & 31;
        int v = vbase - 1 + r;
        float res = 0.0f;
        if (v >= 0 && v < V) {
            float u0 = w1[c * 3 + 0], u1 = w1[c * 3 + 1], u2 = w1[c * 3 + 2];
            float bc = b1[c];
            float w0 = wv2[0], w1_ = wv2[1], w2_ = wv2[2], b = bv2[0];
            const float* base = h3s + r * 32 * 4;
            float4 hh = *(const float4*)(base);
            float xprev = 0.0f;
            float xcur = fmaf(hh.x, u0, fmaf(hh.y, u1, fmaf(hh.z, u2, bc)));
            float s = 0.0f;
            #pragma unroll
            for (int j = 0; j < 32; ++j) {
                float xnext = 0.0f;
                if (j < 31) {
                    float4 hn = *(const float4*)(base + (j + 1) * 4);
                    xnext = fmaf(hn.x, u0, fmaf(hn.y, u1, fmaf(hn.z, u2, bc)));
                }
                float cv = fmaf(w0, xprev, fmaf(w1_, xcur, fmaf(w2_, xnext, b)));
                s += fmaxf(cv, 0.0f);
                xprev = xcur;
                xcur = xnext;
            }
            res = s * (1.0f / 32.0f);
        }
        h2s[r * 32 + c] = res;
    }
    __syncthreads();

    // ---- ph3: kD einsum from h2s -> f2s[32][68] (LDS); 8 waves x 4 rows --
    {
        int o = t & 63;
        int w8 = t >> 6;      // 0..7
        int vb = w8 * 4;
        float bo = b2[o];
        float acc[4];
        #pragma unroll
        for (int m = 0; m < 4; ++m) acc[m] = bo;

        #pragma unroll
        for (int c4 = 0; c4 < 8; ++c4) {
            float4 hv[6];
            #pragma unroll
            for (int r = 0; r < 6; ++r)
                hv[r] = *(const float4*)(h2s + (vb + r) * 32 + c4 * 4);
            #pragma unroll
            for (int k = 0; k < 3; ++k) {
                #pragma unroll
                for (int cc = 0; cc < 4; ++cc) {
                    int c = c4 * 4 + cc;
                    float wv = w2t[(k * 32 + c) * 64 + o];
                    #pragma unroll
                    for (int m = 0; m < 4; ++m) {
                        float hval = (cc == 0) ? hv[m + k].x :
                                     (cc == 1) ? hv[m + k].y :
                                     (cc == 2) ? hv[m + k].z : hv[m + k].w;
                        acc[m] = fmaf(hval, wv, acc[m]);
                    }
                }
            }
        }
        __syncthreads();   // all h3s reads (ph2) complete; safe to alias
        #pragma unroll
        for (int m = 0; m < 4; ++m)
            f2s[(vb + m) * 68 + o] = acc[m];
    }
    __syncthreads();

    // ---- ph4: kE MFMA fc + softmax, SPLIT-K (peak live ~64) ----
    int w8 = t >> 6;         // 0..7
    int set = w8 >> 2;       // row-set 0..1
    int wq = w8 & 3;         // N-quadrant 0..3
    int l = t & 63;
    int c16 = l & 15;
    int g = l >> 4;          // K-group / row-group
    const float* rowp = f2s + (set * 16 + c16) * 68 + g * 8;
    const bf16x8* Bh = (const bf16x8*)wBh;
    const bf16x8* Bm = (const bf16x8*)wBm;
    const bf16x8* Bl = (const bf16x8*)wBl;

    f32x4 acc[8];

#define SPLIT(AH, AM, AL, idx, x) { \
        float xx = (x); \
        unsigned short h_ = f2bf(xx); \
        float r1_ = xx - bf2f(h_); \
        unsigned short m_ = f2bf(r1_); \
        float r2_ = r1_ - bf2f(m_); \
        AH[idx] = (short)h_; AM[idx] = (short)m_; AL[idx] = (short)f2bf(r2_); }

    // ---- phase A: K = 0..31 (s=0 fragments only) ----
    {
        bf16x8 ah, am, al;
        float4 q0 = *(const float4*)(rowp);        // k=g*8..+3
        float4 q1 = *(const float4*)(rowp + 4);    // k=g*8+4..+7
        SPLIT(ah, am, al, 0, q0.x) SPLIT(ah, am, al, 1, q0.y)
        SPLIT(ah, am, al, 2, q0.z) SPLIT(ah, am, al, 3, q0.w)
        SPLIT(ah, am, al, 4, q1.x) SPLIT(ah, am, al, 5, q1.y)
        SPLIT(ah, am, al, 6, q1.z) SPLIT(ah, am, al, 7, q1.w)
        #pragma unroll
        for (int n8 = 0; n8 < 8; ++n8) {
            int n = wq * 8 + n8;
            bf16x8 bh = Bh[(n * 2 + 0) * 64 + l];
            bf16x8 bm = Bm[(n * 2 + 0) * 64 + l];
            bf16x8 bl = Bl[(n * 2 + 0) * 64 + l];
            f32x4 c = {0.f, 0.f, 0.f, 0.f};
            c = __builtin_amdgcn_mfma_f32_16x16x32_bf16(ah, bh, c, 0, 0, 0);
            c = __builtin_amdgcn_mfma_f32_16x16x32_bf16(ah, bm, c, 0, 0, 0);
            c = __builtin_amdgcn_mfma_f32_16x16x32_bf16(am, bh, c, 0, 0, 0);
            c = __builtin_amdgcn_mfma_f32_16x16x32_bf16(ah, bl, c, 0, 0, 0);
            c = __builtin_amdgcn_mfma_f32_16x16x32_bf16(am, bm, c, 0, 0, 0);
            c = __builtin_amdgcn_mfma_f32_16x16x32_bf16(al, bh, c, 0, 0, 0);
            acc[n8] = c;
        }
    }

    // ---- phase B: K = 32..63 (s=1 fragments), then bias ----
    {
        bf16x8 ah, am, al;
        float4 q2 = *(const float4*)(rowp + 32);
        float4 q3 = *(const float4*)(rowp + 36);
        SPLIT(ah, am, al, 0, q2.x) SPLIT(ah, am, al, 1, q2.y)
        SPLIT(ah, am, al, 2, q2.z) SPLIT(ah, am, al, 3, q2.w)
        SPLIT(ah, am, al, 4, q3.x) SPLIT(ah, am, al, 5, q3.y)
        SPLIT(ah, am, al, 6, q3.z) SPLIT(ah, am, al, 7, q3.w)
        #pragma unroll
        for (int n8 = 0; n8 < 8; ++n8) {
            int n = wq * 8 + n8;
            bf16x8 bh = Bh[(n * 2 + 1) * 64 + l];
            bf16x8 bm = Bm[(n * 2 + 1) * 64 + l];
            bf16x8 bl = Bl[(n * 2 + 1) * 64 + l];
            f32x4 c = acc[n8];
            c = __builtin_amdgcn_mfma_f32_16x16x32_bf16(ah, bh, c, 0, 0, 0);
            c = __builtin_amdgcn_mfma_f32_16x16x32_bf16(ah, bm, c, 0, 0, 0);
            c = __builtin_amdgcn_mfma_f32_16x16x32_bf16(am, bh, c, 0, 0, 0);
            c = __builtin_amdgcn_mfma_f32_16x16x32_bf16(ah, bl, c, 0, 0, 0);
            c = __builtin_amdgcn_mfma_f32_16x16x32_bf16(am, bm, c, 0, 0, 0);
            c = __builtin_amdgcn_mfma_f32_16x16x32_bf16(al, bh, c, 0, 0, 0);
            float bn = bfc[n * 16 + c16];
            c.x += bn; c.y += bn; c.z += bn; c.w += bn;
            acc[n8] = c;
        }
    }
#undef SPLIT

    // ---- softmax: rows set*16 + g*4 + j; 16-lane reduce then 4-wave
    //      combine (waves set*4 .. set*4+3) via LDS ----
    float m0 = -1e30f, m1 = -1e30f, m2 = -1e30f, m3 = -1e30f;
    #pragma unroll
    for (int n8 = 0; n8 < 8; ++n8) {
        m0 = fmaxf(m0, acc[n8].x); m1 = fmaxf(m1, acc[n8].y);
        m2 = fmaxf(m2, acc[n8].z); m3 = fmaxf(m3, acc[n8].w);
    }
    #pragma unroll
    for (int off = 8; off; off >>= 1) {
        m0 = fmaxf(m0, __shfl_xor(m0, off));
        m1 = fmaxf(m1, __shfl_xor(m1, off));
        m2 = fmaxf(m2, __shfl_xor(m2, off));
        m3 = fmaxf(m3, __shfl_xor(m3, off));
    }
    if (c16 == 0) {
        redmax[w8][g * 4 + 0] = m0;  redmax[w8][g * 4 + 1] = m1;
        redmax[w8][g * 4 + 2] = m2;  redmax[w8][g * 4 + 3] = m3;
    }
    __syncthreads();
#define GMAX(r) fmaxf(fmaxf(redmax[set * 4 + 0][r], redmax[set * 4 + 1][r]), \
                      fmaxf(redmax[set * 4 + 2][r], redmax[set * 4 + 3][r]))
    float g0 = GMAX(g * 4 + 0), g1 = GMAX(g * 4 + 1);
    float g2 = GMAX(g * 4 + 2), g3 = GMAX(g * 4 + 3);
#undef GMAX

    float s0 = 0.f, s1 = 0.f, s2 = 0.f, s3 = 0.f;
    #pragma unroll
    for (int n8 = 0; n8 < 8; ++n8) {
        acc[n8].x = __expf(acc[n8].x - g0); s0 += acc[n8].x;
        acc[n8].y = __expf(acc[n8].y - g1); s1 += acc[n8].y;
        acc[n8].z = __expf(acc[n8].z - g2); s2 += acc[n8].z;
        acc[n8].w = __expf(acc[n8].w - g3); s3 += acc[n8].w;
    }
    #pragma unroll
    for (int off = 8; off; off >>= 1) {
        s0 += __shfl_xor(s0, off); s1 += __shfl_xor(s1, off);
        s2 += __shfl_xor(s2, off); s3 += __shfl_xor(s3, off);
    }
    if (c16 == 0) {
        redsum[w8][g * 4 + 0] = s0;  redsum[w8][g * 4 + 1] = s1;
        redsum[w8][g * 4 + 2] = s2;  redsum[w8][g * 4 + 3] = s3;
    }
    __syncthreads();
#define GSUM(r) (redsum[set * 4 + 0][r] + redsum[set * 4 + 1][r] + \
                 redsum[set * 4 + 2][r] + redsum[set * 4 + 3][r])
    float i0 = 1.0f / GSUM(g * 4 + 0), i1 = 1.0f / GSUM(g * 4 + 1);
    float i2 = 1.0f / GSUM(g * 4 + 2), i3 = 1.0f / GSUM(g * 4 + 3);
#undef GSUM

    // ---- store: out[(vbase+set*16+g*4+j)*512 + n*16 + c16] ----
    #pragma unroll
    for (int n8 = 0; n8 < 8; ++n8) {
        int n = wq * 8 + n8;
        float* op = out + (size_t)(vbase + set * 16 + g * 4) * 512 + n * 16 + c16;
        __builtin_nontemporal_store(acc[n8].x * i0, op);
        __builtin_nontemporal_store(acc[n8].y * i1, op + 512);
        __builtin_nontemporal_store(acc[n8].z * i2, op + 1024);
        __builtin_nontemporal_store(acc[n8].w * i3, op + 1536);
    }
}

extern "C" void kernel_launch(void* const* d_in, const int* in_sizes, int n_in,
                              void* d_out, int out_size, void* d_ws, size_t ws_size,
                              hipStream_t stream) {
    (void)n_in; (void)out_size; (void)ws_size;
    const float* vp  = (const float*)d_in[0];
    const int*   nb1 = (const int*)d_in[1];
    const int*   nb2 = (const int*)d_in[2];
    const float* wv1 = (const float*)d_in[3];
    const float* bv1 = (const float*)d_in[4];
    const float* w1  = (const float*)d_in[5];
    const float* b1  = (const float*)d_in[6];
    const float* wv2 = (const float*)d_in[7];
    const float* bv2 = (const float*)d_in[8];
    const float* w2  = (const float*)d_in[9];
    const float* b2  = (const float*)d_in[10];
    const float* wfc = (const float*)d_in[11];
    const float* bfc = (const float*)d_in[12];
    float* out = (float*)d_out;
    const int V = in_sizes[0];

    float* ws = (float*)d_ws;
    size_t off = 0;
    float* h    = ws + off; off += (size_t)V;
    float* h3   = ws + off; off += (size_t)V * 4;   // 16B aligned
    float* w2t  = ws + off; off += 3 * 32 * 64;
    short* wBh  = (short*)(ws + off); off += 32768 / 2;   // 32768 shorts
    short* wBm  = (short*)(ws + off); off += 32768 / 2;
    short* wBl  = (short*)(ws + off); off += 32768 / 2;

    k_prep<<<(32768 + 6144 + 255) / 256, 256, 0, stream>>>(wfc, w2, wBh, wBm, wBl, w2t);
    kA<<<(V * 32 + 255) / 256, 256, 0, stream>>>(vp, nb1, wv1, bv1, h, V);
    kB<<<(V + 255) / 256, 256, 0, stream>>>(h, h3, V);
    kF<<<V / 32, 512, 0, stream>>>(h3, nb2, w1, b1, wv2, bv2, w2t, b2,
                                   wBh, wBm, wBl, bfc, out, V);
}

// Round 19
// 349.568 us; speedup vs baseline: 1.1973x; 1.0302x over previous
//
#include <hip/hip_runtime.h>

// ---------------------------------------------------------------------------
// Pipeline:
//  k_prep : w2[64,32,3] -> w2t[3,32,64]; wfc[512,64] -> wB{h,m} bf16 2-way
//  kA     : h[v] = mean_j relu(conv3_j(vp[nb1[v,:]]))               [V]
//  kB     : h3[v] = (h[v-1], h[v], h[v+1], 0)                       [V,4]
//  kF     : FUSED kC+kD+kE per 32-vertex block, 512 THREADS / 8 WAVES
//
// R22 = R21 + ph4 moved from 3-WAY to 2-WAY bf16 split.
// R21 counters: kF 151us, VALUBusy 49% (~74us issue) dominant, MfmaUtil 11%
// (~17us). Error arithmetic: 2-way split x=h+m+r, r~2^-17|x|; products
// {hh,hm,mh} -> logit err ~3e-6 -> softmax output err ~2e-8 absolute --
// 4 orders under the 1.5e-5 absmax (bit-constant across fp32 AND 3-way
// versions -> comparison is insensitive to fc precision). So: 3 MFMA per
// (n8,K-half) not 6 (96->48 MFMA/wave), SPLIT loses a limb, B-frag loads
// -1/3, wBl deleted, ph4 live -~12.
// Verify: absmax stays 1.525879e-05 (else revert); kF -> ~125-135us.
// ---------------------------------------------------------------------------

typedef short bf16x8 __attribute__((ext_vector_type(8)));
typedef float f32x4 __attribute__((ext_vector_type(4)));

__device__ inline unsigned short f2bf(float x) {
    unsigned u = __float_as_uint(x);
    unsigned r = (u + 0x7FFFu + ((u >> 16) & 1u)) >> 16;
    return (unsigned short)r;
}
__device__ inline float bf2f(unsigned short b) {
    return __uint_as_float(((unsigned)b) << 16);
}

// k_prep: w2 transpose + wfc -> 2-way bf16 split in B-fragment order.
__global__ __launch_bounds__(256) void k_prep(const float* __restrict__ wfc,
                                              const float* __restrict__ w2,
                                              short* __restrict__ wBh,
                                              short* __restrict__ wBm,
                                              float* __restrict__ w2t) {
    int t = blockIdx.x * 256 + threadIdx.x;
    if (t < 32768) {
        int j = t & 7;
        int l = (t >> 3) & 63;
        int s = (t >> 9) & 1;
        int n = t >> 10;
        int col = n * 16 + (l & 15);
        int k = s * 32 + (l >> 4) * 8 + j;
        float v = wfc[col * 64 + k];
        unsigned short h = f2bf(v);
        float r1 = v - bf2f(h);
        wBh[t] = (short)h;
        wBm[t] = (short)f2bf(r1);
    } else if (t < 32768 + 6144) {
        int i = t - 32768;
        int o = i / 96;
        int r = i - o * 96;
        int c = r / 3;
        int k = r - c * 3;
        w2t[(k * 32 + c) * 64 + o] = w2[i];
    }
}

// conv1 over neighbor axis: one 32-lane segment per vertex
__global__ __launch_bounds__(256) void kA(const float* __restrict__ vp,
                                          const int* __restrict__ nb1,
                                          const float* __restrict__ wv1,
                                          const float* __restrict__ bv1,
                                          float* __restrict__ h, int V) {
    int t = blockIdx.x * 256 + threadIdx.x;
    int v = t >> 5;
    int j = t & 31;
    if (v >= V) return;
    float g = vp[nb1[v * 32 + j]];
    float gm = __shfl_up(g, 1, 32);
    if (j == 0) gm = 0.0f;
    float gp = __shfl_down(g, 1, 32);
    if (j == 31) gp = 0.0f;
    float c = wv1[0] * gm + wv1[1] * g + wv1[2] * gp + bv1[0];
    c = fmaxf(c, 0.0f);
    #pragma unroll
    for (int off = 16; off; off >>= 1) c += __shfl_xor(c, off, 32);
    if (j == 0) h[v] = c * (1.0f / 32.0f);
}

// h3 builder: h3[v] = (h[v-1], h[v], h[v+1], 0) -- 1.6MB, L2-resident
__global__ __launch_bounds__(256) void kB(const float* __restrict__ h,
                                          float* __restrict__ h3, int V) {
    int v = blockIdx.x * 256 + threadIdx.x;
    if (v >= V) return;
    float hm = (v > 0) ? h[v - 1] : 0.0f;
    float h0 = h[v];
    float hp = (v + 1 < V) ? h[v + 1] : 0.0f;
    *(float4*)(h3 + (size_t)v * 4) = make_float4(hm, h0, hp, 0.0f);
}

// FUSED kC+kD+kE. One block = 32 vertices, 512 threads / 8 waves.
__global__ __launch_bounds__(512) void kF(const float* __restrict__ h3,
                                          const int* __restrict__ nb2,
                                          const float* __restrict__ w1,
                                          const float* __restrict__ b1,
                                          const float* __restrict__ wv2,
                                          const float* __restrict__ bv2,
                                          const float* __restrict__ w2t,
                                          const float* __restrict__ b2,
                                          const short* __restrict__ wBh,
                                          const short* __restrict__ wBm,
                                          const float* __restrict__ bfc,
                                          float* __restrict__ out, int V) {
    __shared__ float h3s[34 * 32 * 4];   // 17408 B; ph3+ aliased as f2s[32][68]
    __shared__ float h2s[34 * 32];       // 4352 B, rows v0-1 .. v0+32
    __shared__ float redmax[8][16];
    __shared__ float redsum[8][16];
    float* f2s = h3s;                    // alias (dead after ph2; barrier-fenced)

    int t = threadIdx.x;
    int vbase = blockIdx.x * 32;

    // ---- ph1: gather h3[nb2[v,j]] for 34 halo rows ----
    for (int i = t; i < 34 * 32; i += 512) {
        int r = i >> 5;                  // tile row, vertex v = vbase-1+r
        int j = i & 31;
        int v = vbase - 1 + r;
        float4 val = make_float4(0.f, 0.f, 0.f, 0.f);
        if (v >= 0 && v < V) {
            int idx = nb2[(size_t)v * 32 + j];
            val = *(const float4*)(h3 + (size_t)idx * 4);
        }
        *(float4*)(h3s + i * 4) = val;
    }
    __syncthreads();

    // ---- ph2: h2[r][c] = mean_j relu(conv3_j(f1_synth)) ----
    for (int i = t; i < 34 * 32; i += 512) {
        int r = i >> 5;
        int c = i & 31;
        int v = vbase - 1 + r;
        float res = 0.0f;
        if (v >= 0 && v < V) {
            float u0 = w1[c * 3 + 0], u1 = w1[c * 3 + 1], u2 = w1[c * 3 + 2];
            float bc = b1[c];
            float w0 = wv2[0], w1_ = wv2[1], w2_ = wv2[2], b = bv2[0];
            const float* base = h3s + r * 32 * 4;
            float4 hh = *(const float4*)(base);
            float xprev = 0.0f;
            float xcur = fmaf(hh.x, u0, fmaf(hh.y, u1, fmaf(hh.z, u2, bc)));
            float s = 0.0f;
            #pragma unroll
            for (int j = 0; j < 32; ++j) {
                float xnext = 0.0f;
                if (j < 31) {
                    float4 hn = *(const float4*)(base + (j + 1) * 4);
                    xnext = fmaf(hn.x, u0, fmaf(hn.y, u1, fmaf(hn.z, u2, bc)));
                }
                float cv = fmaf(w0, xprev, fmaf(w1_, xcur, fmaf(w2_, xnext, b)));
                s += fmaxf(cv, 0.0f);
                xprev = xcur;
                xcur = xnext;
            }
            res = s * (1.0f / 32.0f);
        }
        h2s[r * 32 + c] = res;
    }
    __syncthreads();

    // ---- ph3: kD einsum from h2s -> f2s[32][68] (LDS); 8 waves x 4 rows --
    {
        int o = t & 63;
        int w8 = t >> 6;      // 0..7
        int vb = w8 * 4;
        float bo = b2[o];
        float acc[4];
        #pragma unroll
        for (int m = 0; m < 4; ++m) acc[m] = bo;

        #pragma unroll
        for (int c4 = 0; c4 < 8; ++c4) {
            float4 hv[6];
            #pragma unroll
            for (int r = 0; r < 6; ++r)
                hv[r] = *(const float4*)(h2s + (vb + r) * 32 + c4 * 4);
            #pragma unroll
            for (int k = 0; k < 3; ++k) {
                #pragma unroll
                for (int cc = 0; cc < 4; ++cc) {
                    int c = c4 * 4 + cc;
                    float wv = w2t[(k * 32 + c) * 64 + o];
                    #pragma unroll
                    for (int m = 0; m < 4; ++m) {
                        float hval = (cc == 0) ? hv[m + k].x :
                                     (cc == 1) ? hv[m + k].y :
                                     (cc == 2) ? hv[m + k].z : hv[m + k].w;
                        acc[m] = fmaf(hval, wv, acc[m]);
                    }
                }
            }
        }
        __syncthreads();   // all h3s reads (ph2) complete; safe to alias
        #pragma unroll
        for (int m = 0; m < 4; ++m)
            f2s[(vb + m) * 68 + o] = acc[m];
    }
    __syncthreads();

    // ---- ph4: kE MFMA fc + softmax, SPLIT-K, 2-WAY bf16 split ----
    int w8 = t >> 6;         // 0..7
    int set = w8 >> 2;       // row-set 0..1
    int wq = w8 & 3;         // N-quadrant 0..3
    int l = t & 63;
    int c16 = l & 15;
    int g = l >> 4;          // K-group / row-group
    const float* rowp = f2s + (set * 16 + c16) * 68 + g * 8;
    const bf16x8* Bh = (const bf16x8*)wBh;
    const bf16x8* Bm = (const bf16x8*)wBm;

    f32x4 acc[8];

#define SPLIT(AH, AM, idx, x) { \
        float xx = (x); \
        unsigned short h_ = f2bf(xx); \
        float r1_ = xx - bf2f(h_); \
        AH[idx] = (short)h_; AM[idx] = (short)f2bf(r1_); }

    // ---- phase A: K = 0..31 (s=0 fragments only) ----
    {
        bf16x8 ah, am;
        float4 q0 = *(const float4*)(rowp);        // k=g*8..+3
        float4 q1 = *(const float4*)(rowp + 4);    // k=g*8+4..+7
        SPLIT(ah, am, 0, q0.x) SPLIT(ah, am, 1, q0.y)
        SPLIT(ah, am, 2, q0.z) SPLIT(ah, am, 3, q0.w)
        SPLIT(ah, am, 4, q1.x) SPLIT(ah, am, 5, q1.y)
        SPLIT(ah, am, 6, q1.z) SPLIT(ah, am, 7, q1.w)
        #pragma unroll
        for (int n8 = 0; n8 < 8; ++n8) {
            int n = wq * 8 + n8;
            bf16x8 bh = Bh[(n * 2 + 0) * 64 + l];
            bf16x8 bm = Bm[(n * 2 + 0) * 64 + l];
            f32x4 c = {0.f, 0.f, 0.f, 0.f};
            c = __builtin_amdgcn_mfma_f32_16x16x32_bf16(ah, bh, c, 0, 0, 0);
            c = __builtin_amdgcn_mfma_f32_16x16x32_bf16(ah, bm, c, 0, 0, 0);
            c = __builtin_amdgcn_mfma_f32_16x16x32_bf16(am, bh, c, 0, 0, 0);
            acc[n8] = c;
        }
    }

    // ---- phase B: K = 32..63 (s=1 fragments), then bias ----
    {
        bf16x8 ah, am;
        float4 q2 = *(const float4*)(rowp + 32);
        float4 q3 = *(const float4*)(rowp + 36);
        SPLIT(ah, am, 0, q2.x) SPLIT(ah, am, 1, q2.y)
        SPLIT(ah, am, 2, q2.z) SPLIT(ah, am, 3, q2.w)
        SPLIT(ah, am, 4, q3.x) SPLIT(ah, am, 5, q3.y)
        SPLIT(ah, am, 6, q3.z) SPLIT(ah, am, 7, q3.w)
        #pragma unroll
        for (int n8 = 0; n8 < 8; ++n8) {
            int n = wq * 8 + n8;
            bf16x8 bh = Bh[(n * 2 + 1) * 64 + l];
            bf16x8 bm = Bm[(n * 2 + 1) * 64 + l];
            f32x4 c = acc[n8];
            c = __builtin_amdgcn_mfma_f32_16x16x32_bf16(ah, bh, c, 0, 0, 0);
            c = __builtin_amdgcn_mfma_f32_16x16x32_bf16(ah, bm, c, 0, 0, 0);
            c = __builtin_amdgcn_mfma_f32_16x16x32_bf16(am, bh, c, 0, 0, 0);
            float bn = bfc[n * 16 + c16];
            c.x += bn; c.y += bn; c.z += bn; c.w += bn;
            acc[n8] = c;
        }
    }
#undef SPLIT

    // ---- softmax: rows set*16 + g*4 + j; 16-lane reduce then 4-wave
    //      combine (waves set*4 .. set*4+3) via LDS ----
    float m0 = -1e30f, m1 = -1e30f, m2 = -1e30f, m3 = -1e30f;
    #pragma unroll
    for (int n8 = 0; n8 < 8; ++n8) {
        m0 = fmaxf(m0, acc[n8].x); m1 = fmaxf(m1, acc[n8].y);
        m2 = fmaxf(m2, acc[n8].z); m3 = fmaxf(m3, acc[n8].w);
    }
    #pragma unroll
    for (int off = 8; off; off >>= 1) {
        m0 = fmaxf(m0, __shfl_xor(m0, off));
        m1 = fmaxf(m1, __shfl_xor(m1, off));
        m2 = fmaxf(m2, __shfl_xor(m2, off));
        m3 = fmaxf(m3, __shfl_xor(m3, off));
    }
    if (c16 == 0) {
        redmax[w8][g * 4 + 0] = m0;  redmax[w8][g * 4 + 1] = m1;
        redmax[w8][g * 4 + 2] = m2;  redmax[w8][g * 4 + 3] = m3;
    }
    __syncthreads();
#define GMAX(r) fmaxf(fmaxf(redmax[set * 4 + 0][r], redmax[set * 4 + 1][r]), \
                      fmaxf(redmax[set * 4 + 2][r], redmax[set * 4 + 3][r]))
    float g0 = GMAX(g * 4 + 0), g1 = GMAX(g * 4 + 1);
    float g2 = GMAX(g * 4 + 2), g3 = GMAX(g * 4 + 3);
#undef GMAX

    float s0 = 0.f, s1 = 0.f, s2 = 0.f, s3 = 0.f;
    #pragma unroll
    for (int n8 = 0; n8 < 8; ++n8) {
        acc[n8].x = __expf(acc[n8].x - g0); s0 += acc[n8].x;
        acc[n8].y = __expf(acc[n8].y - g1); s1 += acc[n8].y;
        acc[n8].z = __expf(acc[n8].z - g2); s2 += acc[n8].z;
        acc[n8].w = __expf(acc[n8].w - g3); s3 += acc[n8].w;
    }
    #pragma unroll
    for (int off = 8; off; off >>= 1) {
        s0 += __shfl_xor(s0, off); s1 += __shfl_xor(s1, off);
        s2 += __shfl_xor(s2, off); s3 += __shfl_xor(s3, off);
    }
    if (c16 == 0) {
        redsum[w8][g * 4 + 0] = s0;  redsum[w8][g * 4 + 1] = s1;
        redsum[w8][g * 4 + 2] = s2;  redsum[w8][g * 4 + 3] = s3;
    }
    __syncthreads();
#define GSUM(r) (redsum[set * 4 + 0][r] + redsum[set * 4 + 1][r] + \
                 redsum[set * 4 + 2][r] + redsum[set * 4 + 3][r])
    float i0 = 1.0f / GSUM(g * 4 + 0), i1 = 1.0f / GSUM(g * 4 + 1);
    float i2 = 1.0f / GSUM(g * 4 + 2), i3 = 1.0f / GSUM(g * 4 + 3);
#undef GSUM

    // ---- store: out[(vbase+set*16+g*4+j)*512 + n*16 + c16] ----
    #pragma unroll
    for (int n8 = 0; n8 < 8; ++n8) {
        int n = wq * 8 + n8;
        float* op = out + (size_t)(vbase + set * 16 + g * 4) * 512 + n * 16 + c16;
        __builtin_nontemporal_store(acc[n8].x * i0, op);
        __builtin_nontemporal_store(acc[n8].y * i1, op + 512);
        __builtin_nontemporal_store(acc[n8].z * i2, op + 1024);
        __builtin_nontemporal_store(acc[n8].w * i3, op + 1536);
    }
}

extern "C" void kernel_launch(void* const* d_in, const int* in_sizes, int n_in,
                              void* d_out, int out_size, void* d_ws, size_t ws_size,
                              hipStream_t stream) {
    (void)n_in; (void)out_size; (void)ws_size;
    const float* vp  = (const float*)d_in[0];
    const int*   nb1 = (const int*)d_in[1];
    const int*   nb2 = (const int*)d_in[2];
    const float* wv1 = (const float*)d_in[3];
    const float* bv1 = (const float*)d_in[4];
    const float* w1  = (const float*)d_in[5];
    const float* b1  = (const float*)d_in[6];
    const float* wv2 = (const float*)d_in[7];
    const float* bv2 = (const float*)d_in[8];
    const float* w2  = (const float*)d_in[9];
    const float* b2  = (const float*)d_in[10];
    const float* wfc = (const float*)d_in[11];
    const float* bfc = (const float*)d_in[12];
    float* out = (float*)d_out;
    const int V = in_sizes[0];

    float* ws = (float*)d_ws;
    size_t off = 0;
    float* h    = ws + off; off += (size_t)V;
    float* h3   = ws + off; off += (size_t)V * 4;   // 16B aligned
    float* w2t  = ws + off; off += 3 * 32 * 64;
    short* wBh  = (short*)(ws + off); off += 32768 / 2;   // 32768 shorts
    short* wBm  = (short*)(ws + off); off += 32768 / 2;

    k_prep<<<(32768 + 6144 + 255) / 256, 256, 0, stream>>>(wfc, w2, wBh, wBm, w2t);
    kA<<<(V * 32 + 255) / 256, 256, 0, stream>>>(vp, nb1, wv1, bv1, h, V);
    kB<<<(V + 255) / 256, 256, 0, stream>>>(h, h3, V);
    kF<<<V / 32, 512, 0, stream>>>(h3, nb2, w1, b1, wv2, bv2, w2t, b2,
                                   wBh, wBm, bfc, out, V);
}

// Round 20
// 348.579 us; speedup vs baseline: 1.2007x; 1.0028x over previous
//
#include <hip/hip_runtime.h>

// ---------------------------------------------------------------------------
// Pipeline:
//  k_prep : w2[64,32,3] -> w2t[3,32,64]; wfc[512,64] -> wB{h,m} bf16 2-way
//  kA     : h[v] = mean_j relu(conv3_j(vp[nb1[v,:]]))               [V]
//  kB     : h3[v] = (h[v-1], h[v], h[v+1], 0)                       [V,4]
//  kF     : FUSED kC+kD+kE per 32-vertex block, 512 THREADS / 8 WAVES
//
// R23 = R22 + ph2 STRENGTH-REDUCED via conv-of-affine factoring.
// R22 counters: kF 150us, VALUBusy 45% (~67us), MfmaUtil 5.4% -- halving
// MFMA did nothing; kF is VALU/latency bound and ph2 is the largest VALU
// block (~550 ops/thread, serial synth chain). Factor:
//   cv_j = <w0*hh_{j-1}+w1*hh_j+w2*hh_{j+1}, u_c> + m_j*bc + b,
//   m_j = w0*[j>0]+w1+w2*[j<31]  (hh_{-1}=hh_32=0)
// y_j/m_j are c-INDEPENDENT -> new ph1.5 computes ys[r][j]=(y,m) once per
// (r,j) (1088 items x ~15 ops); ph2 drops to 4 fmaf+max+add per (c,j)
// (8->6 ops, serial chain gone). LDS 23->40KB (cap 3 blk/CU > current 1.7).
// Re-association absmax drift ~1e-7 on 1.5e-5 -- accepted (revert if fail).
// Verify: kF -> ~135-140, total ~335-342.
// ---------------------------------------------------------------------------

typedef short bf16x8 __attribute__((ext_vector_type(8)));
typedef float f32x4 __attribute__((ext_vector_type(4)));

__device__ inline unsigned short f2bf(float x) {
    unsigned u = __float_as_uint(x);
    unsigned r = (u + 0x7FFFu + ((u >> 16) & 1u)) >> 16;
    return (unsigned short)r;
}
__device__ inline float bf2f(unsigned short b) {
    return __uint_as_float(((unsigned)b) << 16);
}

// k_prep: w2 transpose + wfc -> 2-way bf16 split in B-fragment order.
__global__ __launch_bounds__(256) void k_prep(const float* __restrict__ wfc,
                                              const float* __restrict__ w2,
                                              short* __restrict__ wBh,
                                              short* __restrict__ wBm,
                                              float* __restrict__ w2t) {
    int t = blockIdx.x * 256 + threadIdx.x;
    if (t < 32768) {
        int j = t & 7;
        int l = (t >> 3) & 63;
        int s = (t >> 9) & 1;
        int n = t >> 10;
        int col = n * 16 + (l & 15);
        int k = s * 32 + (l >> 4) * 8 + j;
        float v = wfc[col * 64 + k];
        unsigned short h = f2bf(v);
        float r1 = v - bf2f(h);
        wBh[t] = (short)h;
        wBm[t] = (short)f2bf(r1);
    } else if (t < 32768 + 6144) {
        int i = t - 32768;
        int o = i / 96;
        int r = i - o * 96;
        int c = r / 3;
        int k = r - c * 3;
        w2t[(k * 32 + c) * 64 + o] = w2[i];
    }
}

// conv1 over neighbor axis: one 32-lane segment per vertex
__global__ __launch_bounds__(256) void kA(const float* __restrict__ vp,
                                          const int* __restrict__ nb1,
                                          const float* __restrict__ wv1,
                                          const float* __restrict__ bv1,
                                          float* __restrict__ h, int V) {
    int t = blockIdx.x * 256 + threadIdx.x;
    int v = t >> 5;
    int j = t & 31;
    if (v >= V) return;
    float g = vp[nb1[v * 32 + j]];
    float gm = __shfl_up(g, 1, 32);
    if (j == 0) gm = 0.0f;
    float gp = __shfl_down(g, 1, 32);
    if (j == 31) gp = 0.0f;
    float c = wv1[0] * gm + wv1[1] * g + wv1[2] * gp + bv1[0];
    c = fmaxf(c, 0.0f);
    #pragma unroll
    for (int off = 16; off; off >>= 1) c += __shfl_xor(c, off, 32);
    if (j == 0) h[v] = c * (1.0f / 32.0f);
}

// h3 builder: h3[v] = (h[v-1], h[v], h[v+1], 0) -- 1.6MB, L2-resident
__global__ __launch_bounds__(256) void kB(const float* __restrict__ h,
                                          float* __restrict__ h3, int V) {
    int v = blockIdx.x * 256 + threadIdx.x;
    if (v >= V) return;
    float hm = (v > 0) ? h[v - 1] : 0.0f;
    float h0 = h[v];
    float hp = (v + 1 < V) ? h[v + 1] : 0.0f;
    *(float4*)(h3 + (size_t)v * 4) = make_float4(hm, h0, hp, 0.0f);
}

// FUSED kC+kD+kE. One block = 32 vertices, 512 threads / 8 waves.
__global__ __launch_bounds__(512) void kF(const float* __restrict__ h3,
                                          const int* __restrict__ nb2,
                                          const float* __restrict__ w1,
                                          const float* __restrict__ b1,
                                          const float* __restrict__ wv2,
                                          const float* __restrict__ bv2,
                                          const float* __restrict__ w2t,
                                          const float* __restrict__ b2,
                                          const short* __restrict__ wBh,
                                          const short* __restrict__ wBm,
                                          const float* __restrict__ bfc,
                                          float* __restrict__ out, int V) {
    __shared__ float h3s[34 * 32 * 4];   // 17408 B; ph3+ aliased as f2s[32][68]
    __shared__ float ys[34 * 32 * 4];    // 17408 B: (y.x,y.y,y.z,m) per (r,j)
    __shared__ float h2s[34 * 32];       // 4352 B, rows v0-1 .. v0+32
    __shared__ float redmax[8][16];
    __shared__ float redsum[8][16];
    float* f2s = h3s;                    // alias (dead after ph1.5; fenced)

    int t = threadIdx.x;
    int vbase = blockIdx.x * 32;

    // ---- ph1: gather h3[nb2[v,j]] for 34 halo rows ----
    for (int i = t; i < 34 * 32; i += 512) {
        int r = i >> 5;                  // tile row, vertex v = vbase-1+r
        int j = i & 31;
        int v = vbase - 1 + r;
        float4 val = make_float4(0.f, 0.f, 0.f, 0.f);
        if (v >= 0 && v < V) {
            int idx = nb2[(size_t)v * 32 + j];
            val = *(const float4*)(h3 + (size_t)idx * 4);
        }
        *(float4*)(h3s + i * 4) = val;
    }
    __syncthreads();

    // ---- ph1.5: ys[r][j] = (w0*hh[j-1]+w1*hh[j]+w2*hh[j+1], m_j) ----
    {
        float w0 = wv2[0], w1_ = wv2[1], w2_ = wv2[2];
        for (int i = t; i < 34 * 32; i += 512) {
            int j = i & 31;
            const float* base = h3s + (i - j) * 4;   // row start
            float4 h0 = *(const float4*)(base + j * 4);
            float4 hm1 = make_float4(0.f, 0.f, 0.f, 0.f);
            float4 hp1 = make_float4(0.f, 0.f, 0.f, 0.f);
            if (j > 0)  hm1 = *(const float4*)(base + (j - 1) * 4);
            if (j < 31) hp1 = *(const float4*)(base + (j + 1) * 4);
            float4 y;
            y.x = fmaf(w0, hm1.x, fmaf(w1_, h0.x, w2_ * hp1.x));
            y.y = fmaf(w0, hm1.y, fmaf(w1_, h0.y, w2_ * hp1.y));
            y.z = fmaf(w0, hm1.z, fmaf(w1_, h0.z, w2_ * hp1.z));
            y.w = ((j > 0) ? w0 : 0.0f) + w1_ + ((j < 31) ? w2_ : 0.0f);
            *(float4*)(ys + i * 4) = y;
        }
    }
    __syncthreads();

    // ---- ph2: h2[r][c] = mean_j relu(<y_j,u_c> + m_j*bc + b) ----
    for (int i = t; i < 34 * 32; i += 512) {
        int r = i >> 5;
        int c = i & 31;
        int v = vbase - 1 + r;
        float res = 0.0f;
        if (v >= 0 && v < V) {
            float u0 = w1[c * 3 + 0], u1 = w1[c * 3 + 1], u2 = w1[c * 3 + 2];
            float bc = b1[c];
            float b = bv2[0];
            const float* ybase = ys + r * 32 * 4;
            float s = 0.0f;
            #pragma unroll
            for (int j = 0; j < 32; ++j) {
                float4 yv = *(const float4*)(ybase + j * 4);
                float val = fmaf(yv.x, u0, fmaf(yv.y, u1,
                            fmaf(yv.z, u2, fmaf(yv.w, bc, b))));
                s += fmaxf(val, 0.0f);
            }
            res = s * (1.0f / 32.0f);
        }
        h2s[r * 32 + c] = res;
    }
    __syncthreads();

    // ---- ph3: kD einsum from h2s -> f2s[32][68] (LDS); 8 waves x 4 rows --
    {
        int o = t & 63;
        int w8 = t >> 6;      // 0..7
        int vb = w8 * 4;
        float bo = b2[o];
        float acc[4];
        #pragma unroll
        for (int m = 0; m < 4; ++m) acc[m] = bo;

        #pragma unroll
        for (int c4 = 0; c4 < 8; ++c4) {
            float4 hv[6];
            #pragma unroll
            for (int r = 0; r < 6; ++r)
                hv[r] = *(const float4*)(h2s + (vb + r) * 32 + c4 * 4);
            #pragma unroll
            for (int k = 0; k < 3; ++k) {
                #pragma unroll
                for (int cc = 0; cc < 4; ++cc) {
                    int c = c4 * 4 + cc;
                    float wv = w2t[(k * 32 + c) * 64 + o];
                    #pragma unroll
                    for (int m = 0; m < 4; ++m) {
                        float hval = (cc == 0) ? hv[m + k].x :
                                     (cc == 1) ? hv[m + k].y :
                                     (cc == 2) ? hv[m + k].z : hv[m + k].w;
                        acc[m] = fmaf(hval, wv, acc[m]);
                    }
                }
            }
        }
        __syncthreads();   // all h3s/ys reads complete; safe to alias f2s
        #pragma unroll
        for (int m = 0; m < 4; ++m)
            f2s[(vb + m) * 68 + o] = acc[m];
    }
    __syncthreads();

    // ---- ph4: kE MFMA fc + softmax, SPLIT-K, 2-WAY bf16 split ----
    int w8 = t >> 6;         // 0..7
    int set = w8 >> 2;       // row-set 0..1
    int wq = w8 & 3;         // N-quadrant 0..3
    int l = t & 63;
    int c16 = l & 15;
    int g = l >> 4;          // K-group / row-group
    const float* rowp = f2s + (set * 16 + c16) * 68 + g * 8;
    const bf16x8* Bh = (const bf16x8*)wBh;
    const bf16x8* Bm = (const bf16x8*)wBm;

    f32x4 acc[8];

#define SPLIT(AH, AM, idx, x) { \
        float xx = (x); \
        unsigned short h_ = f2bf(xx); \
        float r1_ = xx - bf2f(h_); \
        AH[idx] = (short)h_; AM[idx] = (short)f2bf(r1_); }

    // ---- phase A: K = 0..31 (s=0 fragments only) ----
    {
        bf16x8 ah, am;
        float4 q0 = *(const float4*)(rowp);        // k=g*8..+3
        float4 q1 = *(const float4*)(rowp + 4);    // k=g*8+4..+7
        SPLIT(ah, am, 0, q0.x) SPLIT(ah, am, 1, q0.y)
        SPLIT(ah, am, 2, q0.z) SPLIT(ah, am, 3, q0.w)
        SPLIT(ah, am, 4, q1.x) SPLIT(ah, am, 5, q1.y)
        SPLIT(ah, am, 6, q1.z) SPLIT(ah, am, 7, q1.w)
        #pragma unroll
        for (int n8 = 0; n8 < 8; ++n8) {
            int n = wq * 8 + n8;
            bf16x8 bh = Bh[(n * 2 + 0) * 64 + l];
            bf16x8 bm = Bm[(n * 2 + 0) * 64 + l];
            f32x4 c = {0.f, 0.f, 0.f, 0.f};
            c = __builtin_amdgcn_mfma_f32_16x16x32_bf16(ah, bh, c, 0, 0, 0);
            c = __builtin_amdgcn_mfma_f32_16x16x32_bf16(ah, bm, c, 0, 0, 0);
            c = __builtin_amdgcn_mfma_f32_16x16x32_bf16(am, bh, c, 0, 0, 0);
            acc[n8] = c;
        }
    }

    // ---- phase B: K = 32..63 (s=1 fragments), then bias ----
    {
        bf16x8 ah, am;
        float4 q2 = *(const float4*)(rowp + 32);
        float4 q3 = *(const float4*)(rowp + 36);
        SPLIT(ah, am, 0, q2.x) SPLIT(ah, am, 1, q2.y)
        SPLIT(ah, am, 2, q2.z) SPLIT(ah, am, 3, q2.w)
        SPLIT(ah, am, 4, q3.x) SPLIT(ah, am, 5, q3.y)
        SPLIT(ah, am, 6, q3.z) SPLIT(ah, am, 7, q3.w)
        #pragma unroll
        for (int n8 = 0; n8 < 8; ++n8) {
            int n = wq * 8 + n8;
            bf16x8 bh = Bh[(n * 2 + 1) * 64 + l];
            bf16x8 bm = Bm[(n * 2 + 1) * 64 + l];
            f32x4 c = acc[n8];
            c = __builtin_amdgcn_mfma_f32_16x16x32_bf16(ah, bh, c, 0, 0, 0);
            c = __builtin_amdgcn_mfma_f32_16x16x32_bf16(ah, bm, c, 0, 0, 0);
            c = __builtin_amdgcn_mfma_f32_16x16x32_bf16(am, bh, c, 0, 0, 0);
            float bn = bfc[n * 16 + c16];
            c.x += bn; c.y += bn; c.z += bn; c.w += bn;
            acc[n8] = c;
        }
    }
#undef SPLIT

    // ---- softmax: rows set*16 + g*4 + j; 16-lane reduce then 4-wave
    //      combine (waves set*4 .. set*4+3) via LDS ----
    float m0 = -1e30f, m1 = -1e30f, m2 = -1e30f, m3 = -1e30f;
    #pragma unroll
    for (int n8 = 0; n8 < 8; ++n8) {
        m0 = fmaxf(m0, acc[n8].x); m1 = fmaxf(m1, acc[n8].y);
        m2 = fmaxf(m2, acc[n8].z); m3 = fmaxf(m3, acc[n8].w);
    }
    #pragma unroll
    for (int off = 8; off; off >>= 1) {
        m0 = fmaxf(m0, __shfl_xor(m0, off));
        m1 = fmaxf(m1, __shfl_xor(m1, off));
        m2 = fmaxf(m2, __shfl_xor(m2, off));
        m3 = fmaxf(m3, __shfl_xor(m3, off));
    }
    if (c16 == 0) {
        redmax[w8][g * 4 + 0] = m0;  redmax[w8][g * 4 + 1] = m1;
        redmax[w8][g * 4 + 2] = m2;  redmax[w8][g * 4 + 3] = m3;
    }
    __syncthreads();
#define GMAX(r) fmaxf(fmaxf(redmax[set * 4 + 0][r], redmax[set * 4 + 1][r]), \
                      fmaxf(redmax[set * 4 + 2][r], redmax[set * 4 + 3][r]))
    float g0 = GMAX(g * 4 + 0), g1 = GMAX(g * 4 + 1);
    float g2 = GMAX(g * 4 + 2), g3 = GMAX(g * 4 + 3);
#undef GMAX

    float s0 = 0.f, s1 = 0.f, s2 = 0.f, s3 = 0.f;
    #pragma unroll
    for (int n8 = 0; n8 < 8; ++n8) {
        acc[n8].x = __expf(acc[n8].x - g0); s0 += acc[n8].x;
        acc[n8].y = __expf(acc[n8].y - g1); s1 += acc[n8].y;
        acc[n8].z = __expf(acc[n8].z - g2); s2 += acc[n8].z;
        acc[n8].w = __expf(acc[n8].w - g3); s3 += acc[n8].w;
    }
    #pragma unroll
    for (int off = 8; off; off >>= 1) {
        s0 += __shfl_xor(s0, off); s1 += __shfl_xor(s1, off);
        s2 += __shfl_xor(s2, off); s3 += __shfl_xor(s3, off);
    }
    if (c16 == 0) {
        redsum[w8][g * 4 + 0] = s0;  redsum[w8][g * 4 + 1] = s1;
        redsum[w8][g * 4 + 2] = s2;  redsum[w8][g * 4 + 3] = s3;
    }
    __syncthreads();
#define GSUM(r) (redsum[set * 4 + 0][r] + redsum[set * 4 + 1][r] + \
                 redsum[set * 4 + 2][r] + redsum[set * 4 + 3][r])
    float i0 = 1.0f / GSUM(g * 4 + 0), i1 = 1.0f / GSUM(g * 4 + 1);
    float i2 = 1.0f / GSUM(g * 4 + 2), i3 = 1.0f / GSUM(g * 4 + 3);
#undef GSUM

    // ---- store: out[(vbase+set*16+g*4+j)*512 + n*16 + c16] ----
    #pragma unroll
    for (int n8 = 0; n8 < 8; ++n8) {
        int n = wq * 8 + n8;
        float* op = out + (size_t)(vbase + set * 16 + g * 4) * 512 + n * 16 + c16;
        __builtin_nontemporal_store(acc[n8].x * i0, op);
        __builtin_nontemporal_store(acc[n8].y * i1, op + 512);
        __builtin_nontemporal_store(acc[n8].z * i2, op + 1024);
        __builtin_nontemporal_store(acc[n8].w * i3, op + 1536);
    }
}

extern "C" void kernel_launch(void* const* d_in, const int* in_sizes, int n_in,
                              void* d_out, int out_size, void* d_ws, size_t ws_size,
                              hipStream_t stream) {
    (void)n_in; (void)out_size; (void)ws_size;
    const float* vp  = (const float*)d_in[0];
    const int*   nb1 = (const int*)d_in[1];
    const int*   nb2 = (const int*)d_in[2];
    const float* wv1 = (const float*)d_in[3];
    const float* bv1 = (const float*)d_in[4];
    const float* w1  = (const float*)d_in[5];
    const float* b1  = (const float*)d_in[6];
    const float* wv2 = (const float*)d_in[7];
    const float* bv2 = (const float*)d_in[8];
    const float* w2  = (const float*)d_in[9];
    const float* b2  = (const float*)d_in[10];
    const float* wfc = (const float*)d_in[11];
    const float* bfc = (const float*)d_in[12];
    float* out = (float*)d_out;
    const int V = in_sizes[0];

    float* ws = (float*)d_ws;
    size_t off = 0;
    float* h    = ws + off; off += (size_t)V;
    float* h3   = ws + off; off += (size_t)V * 4;   // 16B aligned
    float* w2t  = ws + off; off += 3 * 32 * 64;
    short* wBh  = (short*)(ws + off); off += 32768 / 2;   // 32768 shorts
    short* wBm  = (short*)(ws + off); off += 32768 / 2;

    k_prep<<<(32768 + 6144 + 255) / 256, 256, 0, stream>>>(wfc, w2, wBh, wBm, w2t);
    kA<<<(V * 32 + 255) / 256, 256, 0, stream>>>(vp, nb1, wv1, bv1, h, V);
    kB<<<(V + 255) / 256, 256, 0, stream>>>(h, h3, V);
    kF<<<V / 32, 512, 0, stream>>>(h3, nb2, w1, b1, wv2, bv2, w2t, b2,
                                   wBh, wBm, bfc, out, V);
}

// Round 21
// 347.716 us; speedup vs baseline: 1.2037x; 1.0025x over previous
//
#include <hip/hip_runtime.h>

// ---------------------------------------------------------------------------
// Pipeline:
//  k_prep : w2[64,32,3] -> w2t[3,32,64]; wfc[512,64] -> wB{h,m} bf16 2-way
//  kA     : h[v] = mean_j relu(conv3_j(vp[nb1[v,:]]))               [V]
//  kB     : h3[v] = (h[v-1], h[v], h[v+1], 0)                       [V,4]
//  kF     : FUSED kC+kD+kE per 32-vertex block, 512 THREADS / 8 WAVES
//
// R24 = R23 + ph1/ph1.5 FUSED via half-wave shfl; h3s LDS buffer deleted.
// R23 counters: kF 137, LDS 40.4KB (cap 3 blk/CU), occ 42%. In ph1 each
// row r's 32 j-entries live in ONE aligned 32-lane group (j = lane&31),
// so hh[j+-1] is in adjacent lanes at gather time: gather -> 6 width-32
// shfls -> y -> ys. Deletes h3s (17.4KB; LDS -> 22.8KB, cap 7 blk/CU),
// 2 barriers (ph1->ph1.5 + ph3 alias fence), ~70KB/blk LDS traffic.
// Same fmaf chains, same bits -> absmax must stay 1.525879e-05.
// f2s aliases ys (dead after ph2, fenced by ph2's barrier).
// Verify: LDS -> 23040, occ -> 55-65%, kF -> ~118-128.
// ---------------------------------------------------------------------------

typedef short bf16x8 __attribute__((ext_vector_type(8)));
typedef float f32x4 __attribute__((ext_vector_type(4)));

__device__ inline unsigned short f2bf(float x) {
    unsigned u = __float_as_uint(x);
    unsigned r = (u + 0x7FFFu + ((u >> 16) & 1u)) >> 16;
    return (unsigned short)r;
}
__device__ inline float bf2f(unsigned short b) {
    return __uint_as_float(((unsigned)b) << 16);
}

// k_prep: w2 transpose + wfc -> 2-way bf16 split in B-fragment order.
__global__ __launch_bounds__(256) void k_prep(const float* __restrict__ wfc,
                                              const float* __restrict__ w2,
                                              short* __restrict__ wBh,
                                              short* __restrict__ wBm,
                                              float* __restrict__ w2t) {
    int t = blockIdx.x * 256 + threadIdx.x;
    if (t < 32768) {
        int j = t & 7;
        int l = (t >> 3) & 63;
        int s = (t >> 9) & 1;
        int n = t >> 10;
        int col = n * 16 + (l & 15);
        int k = s * 32 + (l >> 4) * 8 + j;
        float v = wfc[col * 64 + k];
        unsigned short h = f2bf(v);
        float r1 = v - bf2f(h);
        wBh[t] = (short)h;
        wBm[t] = (short)f2bf(r1);
    } else if (t < 32768 + 6144) {
        int i = t - 32768;
        int o = i / 96;
        int r = i - o * 96;
        int c = r / 3;
        int k = r - c * 3;
        w2t[(k * 32 + c) * 64 + o] = w2[i];
    }
}

// conv1 over neighbor axis: one 32-lane segment per vertex
__global__ __launch_bounds__(256) void kA(const float* __restrict__ vp,
                                          const int* __restrict__ nb1,
                                          const float* __restrict__ wv1,
                                          const float* __restrict__ bv1,
                                          float* __restrict__ h, int V) {
    int t = blockIdx.x * 256 + threadIdx.x;
    int v = t >> 5;
    int j = t & 31;
    if (v >= V) return;
    float g = vp[nb1[v * 32 + j]];
    float gm = __shfl_up(g, 1, 32);
    if (j == 0) gm = 0.0f;
    float gp = __shfl_down(g, 1, 32);
    if (j == 31) gp = 0.0f;
    float c = wv1[0] * gm + wv1[1] * g + wv1[2] * gp + bv1[0];
    c = fmaxf(c, 0.0f);
    #pragma unroll
    for (int off = 16; off; off >>= 1) c += __shfl_xor(c, off, 32);
    if (j == 0) h[v] = c * (1.0f / 32.0f);
}

// h3 builder: h3[v] = (h[v-1], h[v], h[v+1], 0) -- 1.6MB, L2-resident
__global__ __launch_bounds__(256) void kB(const float* __restrict__ h,
                                          float* __restrict__ h3, int V) {
    int v = blockIdx.x * 256 + threadIdx.x;
    if (v >= V) return;
    float hm = (v > 0) ? h[v - 1] : 0.0f;
    float h0 = h[v];
    float hp = (v + 1 < V) ? h[v + 1] : 0.0f;
    *(float4*)(h3 + (size_t)v * 4) = make_float4(hm, h0, hp, 0.0f);
}

// FUSED kC+kD+kE. One block = 32 vertices, 512 threads / 8 waves.
__global__ __launch_bounds__(512) void kF(const float* __restrict__ h3,
                                          const int* __restrict__ nb2,
                                          const float* __restrict__ w1,
                                          const float* __restrict__ b1,
                                          const float* __restrict__ wv2,
                                          const float* __restrict__ bv2,
                                          const float* __restrict__ w2t,
                                          const float* __restrict__ b2,
                                          const short* __restrict__ wBh,
                                          const short* __restrict__ wBm,
                                          const float* __restrict__ bfc,
                                          float* __restrict__ out, int V) {
    __shared__ float ys[34 * 32 * 4];    // 17408 B: (y.x,y.y,y.z,m) per (r,j);
                                         // aliased as f2s[32][68] after ph2
    __shared__ float h2s[34 * 32];       // 4352 B, rows v0-1 .. v0+32
    __shared__ float redmax[8][16];
    __shared__ float redsum[8][16];
    float* f2s = ys;                     // alias (ys dead after ph2; fenced)

    int t = threadIdx.x;
    int vbase = blockIdx.x * 32;

    // ---- ph1 (fused): gather h3[nb2[v,j]] + conv-of-affine y via shfl ----
    // i == t (mod 512) => j = lane&31; row r's 32 entries live in one
    // aligned 32-lane group -> hh[j-1],hh[j+1] via width-32 shfl.
    {
        float w0 = wv2[0], w1_ = wv2[1], w2_ = wv2[2];
        for (int i = t; i < 34 * 32; i += 512) {
            int r = i >> 5;
            int j = i & 31;
            int v = vbase - 1 + r;
            float4 val = make_float4(0.f, 0.f, 0.f, 0.f);
            if (v >= 0 && v < V) {
                int idx = nb2[(size_t)v * 32 + j];
                val = *(const float4*)(h3 + (size_t)idx * 4);
            }
            float hmx = __shfl_up(val.x, 1, 32);
            float hmy = __shfl_up(val.y, 1, 32);
            float hmz = __shfl_up(val.z, 1, 32);
            float hpx = __shfl_down(val.x, 1, 32);
            float hpy = __shfl_down(val.y, 1, 32);
            float hpz = __shfl_down(val.z, 1, 32);
            if (j == 0)  { hmx = 0.f; hmy = 0.f; hmz = 0.f; }
            if (j == 31) { hpx = 0.f; hpy = 0.f; hpz = 0.f; }
            float4 y;
            y.x = fmaf(w0, hmx, fmaf(w1_, val.x, w2_ * hpx));
            y.y = fmaf(w0, hmy, fmaf(w1_, val.y, w2_ * hpy));
            y.z = fmaf(w0, hmz, fmaf(w1_, val.z, w2_ * hpz));
            y.w = ((j > 0) ? w0 : 0.0f) + w1_ + ((j < 31) ? w2_ : 0.0f);
            *(float4*)(ys + i * 4) = y;
        }
    }
    __syncthreads();

    // ---- ph2: h2[r][c] = mean_j relu(<y_j,u_c> + m_j*bc + b) ----
    for (int i = t; i < 34 * 32; i += 512) {
        int r = i >> 5;
        int c = i & 31;
        int v = vbase - 1 + r;
        float res = 0.0f;
        if (v >= 0 && v < V) {
            float u0 = w1[c * 3 + 0], u1 = w1[c * 3 + 1], u2 = w1[c * 3 + 2];
            float bc = b1[c];
            float b = bv2[0];
            const float* ybase = ys + r * 32 * 4;
            float s = 0.0f;
            #pragma unroll
            for (int j = 0; j < 32; ++j) {
                float4 yv = *(const float4*)(ybase + j * 4);
                float val = fmaf(yv.x, u0, fmaf(yv.y, u1,
                            fmaf(yv.z, u2, fmaf(yv.w, bc, b))));
                s += fmaxf(val, 0.0f);
            }
            res = s * (1.0f / 32.0f);
        }
        h2s[r * 32 + c] = res;
    }
    __syncthreads();   // after this, ys has no readers -> f2s alias safe

    // ---- ph3: kD einsum from h2s -> f2s[32][68] (LDS); 8 waves x 4 rows --
    {
        int o = t & 63;
        int w8 = t >> 6;      // 0..7
        int vb = w8 * 4;
        float bo = b2[o];
        float acc[4];
        #pragma unroll
        for (int m = 0; m < 4; ++m) acc[m] = bo;

        #pragma unroll
        for (int c4 = 0; c4 < 8; ++c4) {
            float4 hv[6];
            #pragma unroll
            for (int r = 0; r < 6; ++r)
                hv[r] = *(const float4*)(h2s + (vb + r) * 32 + c4 * 4);
            #pragma unroll
            for (int k = 0; k < 3; ++k) {
                #pragma unroll
                for (int cc = 0; cc < 4; ++cc) {
                    int c = c4 * 4 + cc;
                    float wv = w2t[(k * 32 + c) * 64 + o];
                    #pragma unroll
                    for (int m = 0; m < 4; ++m) {
                        float hval = (cc == 0) ? hv[m + k].x :
                                     (cc == 1) ? hv[m + k].y :
                                     (cc == 2) ? hv[m + k].z : hv[m + k].w;
                        acc[m] = fmaf(hval, wv, acc[m]);
                    }
                }
            }
        }
        #pragma unroll
        for (int m = 0; m < 4; ++m)
            f2s[(vb + m) * 68 + o] = acc[m];
    }
    __syncthreads();

    // ---- ph4: kE MFMA fc + softmax, SPLIT-K, 2-WAY bf16 split ----
    int w8 = t >> 6;         // 0..7
    int set = w8 >> 2;       // row-set 0..1
    int wq = w8 & 3;         // N-quadrant 0..3
    int l = t & 63;
    int c16 = l & 15;
    int g = l >> 4;          // K-group / row-group
    const float* rowp = f2s + (set * 16 + c16) * 68 + g * 8;
    const bf16x8* Bh = (const bf16x8*)wBh;
    const bf16x8* Bm = (const bf16x8*)wBm;

    f32x4 acc[8];

#define SPLIT(AH, AM, idx, x) { \
        float xx = (x); \
        unsigned short h_ = f2bf(xx); \
        float r1_ = xx - bf2f(h_); \
        AH[idx] = (short)h_; AM[idx] = (short)f2bf(r1_); }

    // ---- phase A: K = 0..31 (s=0 fragments only) ----
    {
        bf16x8 ah, am;
        float4 q0 = *(const float4*)(rowp);        // k=g*8..+3
        float4 q1 = *(const float4*)(rowp + 4);    // k=g*8+4..+7
        SPLIT(ah, am, 0, q0.x) SPLIT(ah, am, 1, q0.y)
        SPLIT(ah, am, 2, q0.z) SPLIT(ah, am, 3, q0.w)
        SPLIT(ah, am, 4, q1.x) SPLIT(ah, am, 5, q1.y)
        SPLIT(ah, am, 6, q1.z) SPLIT(ah, am, 7, q1.w)
        #pragma unroll
        for (int n8 = 0; n8 < 8; ++n8) {
            int n = wq * 8 + n8;
            bf16x8 bh = Bh[(n * 2 + 0) * 64 + l];
            bf16x8 bm = Bm[(n * 2 + 0) * 64 + l];
            f32x4 c = {0.f, 0.f, 0.f, 0.f};
            c = __builtin_amdgcn_mfma_f32_16x16x32_bf16(ah, bh, c, 0, 0, 0);
            c = __builtin_amdgcn_mfma_f32_16x16x32_bf16(ah, bm, c, 0, 0, 0);
            c = __builtin_amdgcn_mfma_f32_16x16x32_bf16(am, bh, c, 0, 0, 0);
            acc[n8] = c;
        }
    }

    // ---- phase B: K = 32..63 (s=1 fragments), then bias ----
    {
        bf16x8 ah, am;
        float4 q2 = *(const float4*)(rowp + 32);
        float4 q3 = *(const float4*)(rowp + 36);
        SPLIT(ah, am, 0, q2.x) SPLIT(ah, am, 1, q2.y)
        SPLIT(ah, am, 2, q2.z) SPLIT(ah, am, 3, q2.w)
        SPLIT(ah, am, 4, q3.x) SPLIT(ah, am, 5, q3.y)
        SPLIT(ah, am, 6, q3.z) SPLIT(ah, am, 7, q3.w)
        #pragma unroll
        for (int n8 = 0; n8 < 8; ++n8) {
            int n = wq * 8 + n8;
            bf16x8 bh = Bh[(n * 2 + 1) * 64 + l];
            bf16x8 bm = Bm[(n * 2 + 1) * 64 + l];
            f32x4 c = acc[n8];
            c = __builtin_amdgcn_mfma_f32_16x16x32_bf16(ah, bh, c, 0, 0, 0);
            c = __builtin_amdgcn_mfma_f32_16x16x32_bf16(ah, bm, c, 0, 0, 0);
            c = __builtin_amdgcn_mfma_f32_16x16x32_bf16(am, bh, c, 0, 0, 0);
            float bn = bfc[n * 16 + c16];
            c.x += bn; c.y += bn; c.z += bn; c.w += bn;
            acc[n8] = c;
        }
    }
#undef SPLIT

    // ---- softmax: rows set*16 + g*4 + j; 16-lane reduce then 4-wave
    //      combine (waves set*4 .. set*4+3) via LDS ----
    float m0 = -1e30f, m1 = -1e30f, m2 = -1e30f, m3 = -1e30f;
    #pragma unroll
    for (int n8 = 0; n8 < 8; ++n8) {
        m0 = fmaxf(m0, acc[n8].x); m1 = fmaxf(m1, acc[n8].y);
        m2 = fmaxf(m2, acc[n8].z); m3 = fmaxf(m3, acc[n8].w);
    }
    #pragma unroll
    for (int off = 8; off; off >>= 1) {
        m0 = fmaxf(m0, __shfl_xor(m0, off));
        m1 = fmaxf(m1, __shfl_xor(m1, off));
        m2 = fmaxf(m2, __shfl_xor(m2, off));
        m3 = fmaxf(m3, __shfl_xor(m3, off));
    }
    if (c16 == 0) {
        redmax[w8][g * 4 + 0] = m0;  redmax[w8][g * 4 + 1] = m1;
        redmax[w8][g * 4 + 2] = m2;  redmax[w8][g * 4 + 3] = m3;
    }
    __syncthreads();
#define GMAX(r) fmaxf(fmaxf(redmax[set * 4 + 0][r], redmax[set * 4 + 1][r]), \
                      fmaxf(redmax[set * 4 + 2][r], redmax[set * 4 + 3][r]))
    float g0 = GMAX(g * 4 + 0), g1 = GMAX(g * 4 + 1);
    float g2 = GMAX(g * 4 + 2), g3 = GMAX(g * 4 + 3);
#undef GMAX

    float s0 = 0.f, s1 = 0.f, s2 = 0.f, s3 = 0.f;
    #pragma unroll
    for (int n8 = 0; n8 < 8; ++n8) {
        acc[n8].x = __expf(acc[n8].x - g0); s0 += acc[n8].x;
        acc[n8].y = __expf(acc[n8].y - g1); s1 += acc[n8].y;
        acc[n8].z = __expf(acc[n8].z - g2); s2 += acc[n8].z;
        acc[n8].w = __expf(acc[n8].w - g3); s3 += acc[n8].w;
    }
    #pragma unroll
    for (int off = 8; off; off >>= 1) {
        s0 += __shfl_xor(s0, off); s1 += __shfl_xor(s1, off);
        s2 += __shfl_xor(s2, off); s3 += __shfl_xor(s3, off);
    }
    if (c16 == 0) {
        redsum[w8][g * 4 + 0] = s0;  redsum[w8][g * 4 + 1] = s1;
        redsum[w8][g * 4 + 2] = s2;  redsum[w8][g * 4 + 3] = s3;
    }
    __syncthreads();
#define GSUM(r) (redsum[set * 4 + 0][r] + redsum[set * 4 + 1][r] + \
                 redsum[set * 4 + 2][r] + redsum[set * 4 + 3][r])
    float i0 = 1.0f / GSUM(g * 4 + 0), i1 = 1.0f / GSUM(g * 4 + 1);
    float i2 = 1.0f / GSUM(g * 4 + 2), i3 = 1.0f / GSUM(g * 4 + 3);
#undef GSUM

    // ---- store: out[(vbase+set*16+g*4+j)*512 + n*16 + c16] ----
    #pragma unroll
    for (int n8 = 0; n8 < 8; ++n8) {
        int n = wq * 8 + n8;
        float* op = out + (size_t)(vbase + set * 16 + g * 4) * 512 + n * 16 + c16;
        __builtin_nontemporal_store(acc[n8].x * i0, op);
        __builtin_nontemporal_store(acc[n8].y * i1, op + 512);
        __builtin_nontemporal_store(acc[n8].z * i2, op + 1024);
        __builtin_nontemporal_store(acc[n8].w * i3, op + 1536);
    }
}

extern "C" void kernel_launch(void* const* d_in, const int* in_sizes, int n_in,
                              void* d_out, int out_size, void* d_ws, size_t ws_size,
                              hipStream_t stream) {
    (void)n_in; (void)out_size; (void)ws_size;
    const float* vp  = (const float*)d_in[0];
    const int*   nb1 = (const int*)d_in[1];
    const int*   nb2 = (const int*)d_in[2];
    const float* wv1 = (const float*)d_in[3];
    const float* bv1 = (const float*)d_in[4];
    const float* w1  = (const float*)d_in[5];
    const float* b1  = (const float*)d_in[6];
    const float* wv2 = (const float*)d_in[7];
    const float* bv2 = (const float*)d_in[8];
    const float* w2  = (const float*)d_in[9];
    const float* b2  = (const float*)d_in[10];
    const float* wfc = (const float*)d_in[11];
    const float* bfc = (const float*)d_in[12];
    float* out = (float*)d_out;
    const int V = in_sizes[0];

    float* ws = (float*)d_ws;
    size_t off = 0;
    float* h    = ws + off; off += (size_t)V;
    float* h3   = ws + off; off += (size_t)V * 4;   // 16B aligned
    float* w2t  = ws + off; off += 3 * 32 * 64;
    short* wBh  = (short*)(ws + off); off += 32768 / 2;   // 32768 shorts
    short* wBm  = (short*)(ws + off); off += 32768 / 2;

    k_prep<<<(32768 + 6144 + 255) / 256, 256, 0, stream>>>(wfc, w2, wBh, wBm, w2t);
    kA<<<(V * 32 + 255) / 256, 256, 0, stream>>>(vp, nb1, wv1, bv1, h, V);
    kB<<<(V + 255) / 256, 256, 0, stream>>>(h, h3, V);
    kF<<<V / 32, 512, 0, stream>>>(h3, nb2, w1, b1, wv2, bv2, w2t, b2,
                                   wBh, wBm, bfc, out, V);
}

// Round 22
// 344.445 us; speedup vs baseline: 1.2151x; 1.0095x over previous
//
#include <hip/hip_runtime.h>

// ---------------------------------------------------------------------------
// Pipeline:
//  k_prep : w2[64,32,3] -> w2t[3,32,64]; wfc[512,64] -> wB{h,m} bf16 2-way
//  kA     : h[v] = mean_j relu(conv3_j(vp[nb1[v,:]]))               [V]
//  kB     : h3[v] = (h[v-1], h[v], h[v+1], 0)                       [V,4]
//  kF     : FUSED kC+kD+kE per 32-vertex block, 512 THREADS / 8 WAVES
//
// R25 = R24 + kA REWRITTEN (first touch in 21 rounds).
// Ledger: kF now 133us but total 347.7 -- subtraction puts kA at ~100-130us
// (never in top-5: the fillBuffer/kF cut was always >=120). Old kA = 32
// lanes/vertex -> MLP=1 random vp gather per lane + 5-step serial shfl
// reduce: the exact R4 disease. New kA = one vertex per THREAD (R10's +MLP
// direction): 8 int4 nb1 loads, 32 INDEPENDENT vp gathers in flight,
// conv+relu+mean lane-local, zero shuffles. ~50 live VGPR.
// Sum association changes (sequential vs butterfly): drift ~1e-7 vs the
// 1.5e-5 absmax margin -- accepted.
// Verify: total 347.7 -> ~290-310 (kA invisible directly). If <10us moved,
// kA was small and remaining time is harness overhead -> plateau next.
// ---------------------------------------------------------------------------

typedef short bf16x8 __attribute__((ext_vector_type(8)));
typedef float f32x4 __attribute__((ext_vector_type(4)));

__device__ inline unsigned short f2bf(float x) {
    unsigned u = __float_as_uint(x);
    unsigned r = (u + 0x7FFFu + ((u >> 16) & 1u)) >> 16;
    return (unsigned short)r;
}
__device__ inline float bf2f(unsigned short b) {
    return __uint_as_float(((unsigned)b) << 16);
}

// k_prep: w2 transpose + wfc -> 2-way bf16 split in B-fragment order.
__global__ __launch_bounds__(256) void k_prep(const float* __restrict__ wfc,
                                              const float* __restrict__ w2,
                                              short* __restrict__ wBh,
                                              short* __restrict__ wBm,
                                              float* __restrict__ w2t) {
    int t = blockIdx.x * 256 + threadIdx.x;
    if (t < 32768) {
        int j = t & 7;
        int l = (t >> 3) & 63;
        int s = (t >> 9) & 1;
        int n = t >> 10;
        int col = n * 16 + (l & 15);
        int k = s * 32 + (l >> 4) * 8 + j;
        float v = wfc[col * 64 + k];
        unsigned short h = f2bf(v);
        float r1 = v - bf2f(h);
        wBh[t] = (short)h;
        wBm[t] = (short)f2bf(r1);
    } else if (t < 32768 + 6144) {
        int i = t - 32768;
        int o = i / 96;
        int r = i - o * 96;
        int c = r / 3;
        int k = r - c * 3;
        w2t[(k * 32 + c) * 64 + o] = w2[i];
    }
}

// conv1: ONE VERTEX PER THREAD. 8 int4 nb1 loads, 32 independent vp
// gathers in flight (vp is 400KB L2-resident), conv+relu+mean lane-local.
__global__ __launch_bounds__(256) void kA(const float* __restrict__ vp,
                                          const int* __restrict__ nb1,
                                          const float* __restrict__ wv1,
                                          const float* __restrict__ bv1,
                                          float* __restrict__ h, int V) {
    int v = blockIdx.x * 256 + threadIdx.x;
    if (v >= V) return;
    const int* nb = nb1 + (size_t)v * 32;

    int idx[32];
    #pragma unroll
    for (int q = 0; q < 8; ++q) {
        int4 t4 = *(const int4*)(nb + q * 4);
        idx[q * 4 + 0] = t4.x;
        idx[q * 4 + 1] = t4.y;
        idx[q * 4 + 2] = t4.z;
        idx[q * 4 + 3] = t4.w;
    }
    float x[32];
    #pragma unroll
    for (int j = 0; j < 32; ++j)
        x[j] = vp[idx[j]];

    float w0 = wv1[0], w1_ = wv1[1], w2_ = wv1[2], b = bv1[0];
    float s = 0.0f;
    #pragma unroll
    for (int j = 0; j < 32; ++j) {
        float pv = (j > 0)  ? x[j - 1] : 0.0f;
        float nx = (j < 31) ? x[j + 1] : 0.0f;
        float cv = fmaf(w0, pv, fmaf(w1_, x[j], fmaf(w2_, nx, b)));
        s += fmaxf(cv, 0.0f);
    }
    h[v] = s * (1.0f / 32.0f);
}

// h3 builder: h3[v] = (h[v-1], h[v], h[v+1], 0) -- 1.6MB, L2-resident
__global__ __launch_bounds__(256) void kB(const float* __restrict__ h,
                                          float* __restrict__ h3, int V) {
    int v = blockIdx.x * 256 + threadIdx.x;
    if (v >= V) return;
    float hm = (v > 0) ? h[v - 1] : 0.0f;
    float h0 = h[v];
    float hp = (v + 1 < V) ? h[v + 1] : 0.0f;
    *(float4*)(h3 + (size_t)v * 4) = make_float4(hm, h0, hp, 0.0f);
}

// FUSED kC+kD+kE. One block = 32 vertices, 512 threads / 8 waves.
__global__ __launch_bounds__(512) void kF(const float* __restrict__ h3,
                                          const int* __restrict__ nb2,
                                          const float* __restrict__ w1,
                                          const float* __restrict__ b1,
                                          const float* __restrict__ wv2,
                                          const float* __restrict__ bv2,
                                          const float* __restrict__ w2t,
                                          const float* __restrict__ b2,
                                          const short* __restrict__ wBh,
                                          const short* __restrict__ wBm,
                                          const float* __restrict__ bfc,
                                          float* __restrict__ out, int V) {
    __shared__ float ys[34 * 32 * 4];    // 17408 B: (y.x,y.y,y.z,m) per (r,j);
                                         // aliased as f2s[32][68] after ph2
    __shared__ float h2s[34 * 32];       // 4352 B, rows v0-1 .. v0+32
    __shared__ float redmax[8][16];
    __shared__ float redsum[8][16];
    float* f2s = ys;                     // alias (ys dead after ph2; fenced)

    int t = threadIdx.x;
    int vbase = blockIdx.x * 32;

    // ---- ph1 (fused): gather h3[nb2[v,j]] + conv-of-affine y via shfl ----
    {
        float w0 = wv2[0], w1_ = wv2[1], w2_ = wv2[2];
        for (int i = t; i < 34 * 32; i += 512) {
            int r = i >> 5;
            int j = i & 31;
            int v = vbase - 1 + r;
            float4 val = make_float4(0.f, 0.f, 0.f, 0.f);
            if (v >= 0 && v < V) {
                int idx = nb2[(size_t)v * 32 + j];
                val = *(const float4*)(h3 + (size_t)idx * 4);
            }
            float hmx = __shfl_up(val.x, 1, 32);
            float hmy = __shfl_up(val.y, 1, 32);
            float hmz = __shfl_up(val.z, 1, 32);
            float hpx = __shfl_down(val.x, 1, 32);
            float hpy = __shfl_down(val.y, 1, 32);
            float hpz = __shfl_down(val.z, 1, 32);
            if (j == 0)  { hmx = 0.f; hmy = 0.f; hmz = 0.f; }
            if (j == 31) { hpx = 0.f; hpy = 0.f; hpz = 0.f; }
            float4 y;
            y.x = fmaf(w0, hmx, fmaf(w1_, val.x, w2_ * hpx));
            y.y = fmaf(w0, hmy, fmaf(w1_, val.y, w2_ * hpy));
            y.z = fmaf(w0, hmz, fmaf(w1_, val.z, w2_ * hpz));
            y.w = ((j > 0) ? w0 : 0.0f) + w1_ + ((j < 31) ? w2_ : 0.0f);
            *(float4*)(ys + i * 4) = y;
        }
    }
    __syncthreads();

    // ---- ph2: h2[r][c] = mean_j relu(<y_j,u_c> + m_j*bc + b) ----
    for (int i = t; i < 34 * 32; i += 512) {
        int r = i >> 5;
        int c = i & 31;
        int v = vbase - 1 + r;
        float res = 0.0f;
        if (v >= 0 && v < V) {
            float u0 = w1[c * 3 + 0], u1 = w1[c * 3 + 1], u2 = w1[c * 3 + 2];
            float bc = b1[c];
            float b = bv2[0];
            const float* ybase = ys + r * 32 * 4;
            float s = 0.0f;
            #pragma unroll
            for (int j = 0; j < 32; ++j) {
                float4 yv = *(const float4*)(ybase + j * 4);
                float val = fmaf(yv.x, u0, fmaf(yv.y, u1,
                            fmaf(yv.z, u2, fmaf(yv.w, bc, b))));
                s += fmaxf(val, 0.0f);
            }
            res = s * (1.0f / 32.0f);
        }
        h2s[r * 32 + c] = res;
    }
    __syncthreads();   // after this, ys has no readers -> f2s alias safe

    // ---- ph3: kD einsum from h2s -> f2s[32][68] (LDS); 8 waves x 4 rows --
    {
        int o = t & 63;
        int w8 = t >> 6;      // 0..7
        int vb = w8 * 4;
        float bo = b2[o];
        float acc[4];
        #pragma unroll
        for (int m = 0; m < 4; ++m) acc[m] = bo;

        #pragma unroll
        for (int c4 = 0; c4 < 8; ++c4) {
            float4 hv[6];
            #pragma unroll
            for (int r = 0; r < 6; ++r)
                hv[r] = *(const float4*)(h2s + (vb + r) * 32 + c4 * 4);
            #pragma unroll
            for (int k = 0; k < 3; ++k) {
                #pragma unroll
                for (int cc = 0; cc < 4; ++cc) {
                    int c = c4 * 4 + cc;
                    float wv = w2t[(k * 32 + c) * 64 + o];
                    #pragma unroll
                    for (int m = 0; m < 4; ++m) {
                        float hval = (cc == 0) ? hv[m + k].x :
                                     (cc == 1) ? hv[m + k].y :
                                     (cc == 2) ? hv[m + k].z : hv[m + k].w;
                        acc[m] = fmaf(hval, wv, acc[m]);
                    }
                }
            }
        }
        #pragma unroll
        for (int m = 0; m < 4; ++m)
            f2s[(vb + m) * 68 + o] = acc[m];
    }
    __syncthreads();

    // ---- ph4: kE MFMA fc + softmax, SPLIT-K, 2-WAY bf16 split ----
    int w8 = t >> 6;         // 0..7
    int set = w8 >> 2;       // row-set 0..1
    int wq = w8 & 3;         // N-quadrant 0..3
    int l = t & 63;
    int c16 = l & 15;
    int g = l >> 4;          // K-group / row-group
    const float* rowp = f2s + (set * 16 + c16) * 68 + g * 8;
    const bf16x8* Bh = (const bf16x8*)wBh;
    const bf16x8* Bm = (const bf16x8*)wBm;

    f32x4 acc[8];

#define SPLIT(AH, AM, idx, x) { \
        float xx = (x); \
        unsigned short h_ = f2bf(xx); \
        float r1_ = xx - bf2f(h_); \
        AH[idx] = (short)h_; AM[idx] = (short)f2bf(r1_); }

    // ---- phase A: K = 0..31 (s=0 fragments only) ----
    {
        bf16x8 ah, am;
        float4 q0 = *(const float4*)(rowp);        // k=g*8..+3
        float4 q1 = *(const float4*)(rowp + 4);    // k=g*8+4..+7
        SPLIT(ah, am, 0, q0.x) SPLIT(ah, am, 1, q0.y)
        SPLIT(ah, am, 2, q0.z) SPLIT(ah, am, 3, q0.w)
        SPLIT(ah, am, 4, q1.x) SPLIT(ah, am, 5, q1.y)
        SPLIT(ah, am, 6, q1.z) SPLIT(ah, am, 7, q1.w)
        #pragma unroll
        for (int n8 = 0; n8 < 8; ++n8) {
            int n = wq * 8 + n8;
            bf16x8 bh = Bh[(n * 2 + 0) * 64 + l];
            bf16x8 bm = Bm[(n * 2 + 0) * 64 + l];
            f32x4 c = {0.f, 0.f, 0.f, 0.f};
            c = __builtin_amdgcn_mfma_f32_16x16x32_bf16(ah, bh, c, 0, 0, 0);
            c = __builtin_amdgcn_mfma_f32_16x16x32_bf16(ah, bm, c, 0, 0, 0);
            c = __builtin_amdgcn_mfma_f32_16x16x32_bf16(am, bh, c, 0, 0, 0);
            acc[n8] = c;
        }
    }

    // ---- phase B: K = 32..63 (s=1 fragments), then bias ----
    {
        bf16x8 ah, am;
        float4 q2 = *(const float4*)(rowp + 32);
        float4 q3 = *(const float4*)(rowp + 36);
        SPLIT(ah, am, 0, q2.x) SPLIT(ah, am, 1, q2.y)
        SPLIT(ah, am, 2, q2.z) SPLIT(ah, am, 3, q2.w)
        SPLIT(ah, am, 4, q3.x) SPLIT(ah, am, 5, q3.y)
        SPLIT(ah, am, 6, q3.z) SPLIT(ah, am, 7, q3.w)
        #pragma unroll
        for (int n8 = 0; n8 < 8; ++n8) {
            int n = wq * 8 + n8;
            bf16x8 bh = Bh[(n * 2 + 1) * 64 + l];
            bf16x8 bm = Bm[(n * 2 + 1) * 64 + l];
            f32x4 c = acc[n8];
            c = __builtin_amdgcn_mfma_f32_16x16x32_bf16(ah, bh, c, 0, 0, 0);
            c = __builtin_amdgcn_mfma_f32_16x16x32_bf16(ah, bm, c, 0, 0, 0);
            c = __builtin_amdgcn_mfma_f32_16x16x32_bf16(am, bh, c, 0, 0, 0);
            float bn = bfc[n * 16 + c16];
            c.x += bn; c.y += bn; c.z += bn; c.w += bn;
            acc[n8] = c;
        }
    }
#undef SPLIT

    // ---- softmax: rows set*16 + g*4 + j; 16-lane reduce then 4-wave
    //      combine (waves set*4 .. set*4+3) via LDS ----
    float m0 = -1e30f, m1 = -1e30f, m2 = -1e30f, m3 = -1e30f;
    #pragma unroll
    for (int n8 = 0; n8 < 8; ++n8) {
        m0 = fmaxf(m0, acc[n8].x); m1 = fmaxf(m1, acc[n8].y);
        m2 = fmaxf(m2, acc[n8].z); m3 = fmaxf(m3, acc[n8].w);
    }
    #pragma unroll
    for (int off = 8; off; off >>= 1) {
        m0 = fmaxf(m0, __shfl_xor(m0, off));
        m1 = fmaxf(m1, __shfl_xor(m1, off));
        m2 = fmaxf(m2, __shfl_xor(m2, off));
        m3 = fmaxf(m3, __shfl_xor(m3, off));
    }
    if (c16 == 0) {
        redmax[w8][g * 4 + 0] = m0;  redmax[w8][g * 4 + 1] = m1;
        redmax[w8][g * 4 + 2] = m2;  redmax[w8][g * 4 + 3] = m3;
    }
    __syncthreads();
#define GMAX(r) fmaxf(fmaxf(redmax[set * 4 + 0][r], redmax[set * 4 + 1][r]), \
                      fmaxf(redmax[set * 4 + 2][r], redmax[set * 4 + 3][r]))
    float g0 = GMAX(g * 4 + 0), g1 = GMAX(g * 4 + 1);
    float g2 = GMAX(g * 4 + 2), g3 = GMAX(g * 4 + 3);
#undef GMAX

    float s0 = 0.f, s1 = 0.f, s2 = 0.f, s3 = 0.f;
    #pragma unroll
    for (int n8 = 0; n8 < 8; ++n8) {
        acc[n8].x = __expf(acc[n8].x - g0); s0 += acc[n8].x;
        acc[n8].y = __expf(acc[n8].y - g1); s1 += acc[n8].y;
        acc[n8].z = __expf(acc[n8].z - g2); s2 += acc[n8].z;
        acc[n8].w = __expf(acc[n8].w - g3); s3 += acc[n8].w;
    }
    #pragma unroll
    for (int off = 8; off; off >>= 1) {
        s0 += __shfl_xor(s0, off); s1 += __shfl_xor(s1, off);
        s2 += __shfl_xor(s2, off); s3 += __shfl_xor(s3, off);
    }
    if (c16 == 0) {
        redsum[w8][g * 4 + 0] = s0;  redsum[w8][g * 4 + 1] = s1;
        redsum[w8][g * 4 + 2] = s2;  redsum[w8][g * 4 + 3] = s3;
    }
    __syncthreads();
#define GSUM(r) (redsum[set * 4 + 0][r] + redsum[set * 4 + 1][r] + \
                 redsum[set * 4 + 2][r] + redsum[set * 4 + 3][r])
    float i0 = 1.0f / GSUM(g * 4 + 0), i1 = 1.0f / GSUM(g * 4 + 1);
    float i2 = 1.0f / GSUM(g * 4 + 2), i3 = 1.0f / GSUM(g * 4 + 3);
#undef GSUM

    // ---- store: out[(vbase+set*16+g*4+j)*512 + n*16 + c16] ----
    #pragma unroll
    for (int n8 = 0; n8 < 8; ++n8) {
        int n = wq * 8 + n8;
        float* op = out + (size_t)(vbase + set * 16 + g * 4) * 512 + n * 16 + c16;
        __builtin_nontemporal_store(acc[n8].x * i0, op);
        __builtin_nontemporal_store(acc[n8].y * i1, op + 512);
        __builtin_nontemporal_store(acc[n8].z * i2, op + 1024);
        __builtin_nontemporal_store(acc[n8].w * i3, op + 1536);
    }
}

extern "C" void kernel_launch(void* const* d_in, const int* in_sizes, int n_in,
                              void* d_out, int out_size, void* d_ws, size_t ws_size,
                              hipStream_t stream) {
    (void)n_in; (void)out_size; (void)ws_size;
    const float* vp  = (const float*)d_in[0];
    const int*   nb1 = (const int*)d_in[1];
    const int*   nb2 = (const int*)d_in[2];
    const float* wv1 = (const float*)d_in[3];
    const float* bv1 = (const float*)d_in[4];
    const float* w1  = (const float*)d_in[5];
    const float* b1  = (const float*)d_in[6];
    const float* wv2 = (const float*)d_in[7];
    const float* bv2 = (const float*)d_in[8];
    const float* w2  = (const float*)d_in[9];
    const float* b2  = (const float*)d_in[10];
    const float* wfc = (const float*)d_in[11];
    const float* bfc = (const float*)d_in[12];
    float* out = (float*)d_out;
    const int V = in_sizes[0];

    float* ws = (float*)d_ws;
    size_t off = 0;
    float* h    = ws + off; off += (size_t)V;
    float* h3   = ws + off; off += (size_t)V * 4;   // 16B aligned
    float* w2t  = ws + off; off += 3 * 32 * 64;
    short* wBh  = (short*)(ws + off); off += 32768 / 2;   // 32768 shorts
    short* wBm  = (short*)(ws + off); off += 32768 / 2;

    k_prep<<<(32768 + 6144 + 255) / 256, 256, 0, stream>>>(wfc, w2, wBh, wBm, w2t);
    kA<<<(V + 255) / 256, 256, 0, stream>>>(vp, nb1, wv1, bv1, h, V);
    kB<<<(V + 255) / 256, 256, 0, stream>>>(h, h3, V);
    kF<<<V / 32, 512, 0, stream>>>(h3, nb2, w1, b1, wv2, bv2, w2t, b2,
                                   wBh, wBm, bfc, out, V);
}

// Round 23
// 340.342 us; speedup vs baseline: 1.2298x; 1.0121x over previous
//
#include <hip/hip_runtime.h>

// ---------------------------------------------------------------------------
// Pipeline:
//  k_prep : w2[64,32,3] -> w2t[3,32,64]; wfc[512,64] -> wB{h,m} bf16 2-way
//  kA     : h[v] = mean_j relu(conv3_j(vp[nb1[v,:]]))               [V]
//  kB     : h3[v] = (h[v-1], h[v], h[v+1], 0)                       [V,4]
//  kF     : FUSED kC+kD+kE per 16-vertex block, 256 THREADS / 4 WAVES
//
// R26: kF reshaped 32v/512t -> 16v/256t. R22 ledger: the allocator pins
// ~48 VGPR for EVERY 512-thread build (R16-R22, immune to launch_bounds)
// vs ~65-70 peak live -> ~40MB spill; per-thread scratch is what caps
// occupancy at 42%. The one config that got a 96-VGPR budget: R12's
// 256-THREAD block. Same math, halved geometry: 18-row halo, ph3 = 4
// waves x 4 rows, ph4 = 4 waves x one N-quadrant (8 tiles) of the single
// 16-row set; softmax combines across all 4 waves. B-frag traffic x2
// (R9: free). LDS ~12.2KB. Bit-identical chains -> absmax 1.525879e-05.
// Verify: VGPR -> ~96 (key), WRITE -> ~205MB, occ -> 55-70%, kF ~100-115.
// ---------------------------------------------------------------------------

typedef short bf16x8 __attribute__((ext_vector_type(8)));
typedef float f32x4 __attribute__((ext_vector_type(4)));

__device__ inline unsigned short f2bf(float x) {
    unsigned u = __float_as_uint(x);
    unsigned r = (u + 0x7FFFu + ((u >> 16) & 1u)) >> 16;
    return (unsigned short)r;
}
__device__ inline float bf2f(unsigned short b) {
    return __uint_as_float(((unsigned)b) << 16);
}

// k_prep: w2 transpose + wfc -> 2-way bf16 split in B-fragment order.
__global__ __launch_bounds__(256) void k_prep(const float* __restrict__ wfc,
                                              const float* __restrict__ w2,
                                              short* __restrict__ wBh,
                                              short* __restrict__ wBm,
                                              float* __restrict__ w2t) {
    int t = blockIdx.x * 256 + threadIdx.x;
    if (t < 32768) {
        int j = t & 7;
        int l = (t >> 3) & 63;
        int s = (t >> 9) & 1;
        int n = t >> 10;
        int col = n * 16 + (l & 15);
        int k = s * 32 + (l >> 4) * 8 + j;
        float v = wfc[col * 64 + k];
        unsigned short h = f2bf(v);
        float r1 = v - bf2f(h);
        wBh[t] = (short)h;
        wBm[t] = (short)f2bf(r1);
    } else if (t < 32768 + 6144) {
        int i = t - 32768;
        int o = i / 96;
        int r = i - o * 96;
        int c = r / 3;
        int k = r - c * 3;
        w2t[(k * 32 + c) * 64 + o] = w2[i];
    }
}

// conv1: one vertex per thread, 32 independent vp gathers in flight.
__global__ __launch_bounds__(256) void kA(const float* __restrict__ vp,
                                          const int* __restrict__ nb1,
                                          const float* __restrict__ wv1,
                                          const float* __restrict__ bv1,
                                          float* __restrict__ h, int V) {
    int v = blockIdx.x * 256 + threadIdx.x;
    if (v >= V) return;
    const int* nb = nb1 + (size_t)v * 32;

    int idx[32];
    #pragma unroll
    for (int q = 0; q < 8; ++q) {
        int4 t4 = *(const int4*)(nb + q * 4);
        idx[q * 4 + 0] = t4.x;
        idx[q * 4 + 1] = t4.y;
        idx[q * 4 + 2] = t4.z;
        idx[q * 4 + 3] = t4.w;
    }
    float x[32];
    #pragma unroll
    for (int j = 0; j < 32; ++j)
        x[j] = vp[idx[j]];

    float w0 = wv1[0], w1_ = wv1[1], w2_ = wv1[2], b = bv1[0];
    float s = 0.0f;
    #pragma unroll
    for (int j = 0; j < 32; ++j) {
        float pv = (j > 0)  ? x[j - 1] : 0.0f;
        float nx = (j < 31) ? x[j + 1] : 0.0f;
        float cv = fmaf(w0, pv, fmaf(w1_, x[j], fmaf(w2_, nx, b)));
        s += fmaxf(cv, 0.0f);
    }
    h[v] = s * (1.0f / 32.0f);
}

// h3 builder: h3[v] = (h[v-1], h[v], h[v+1], 0) -- 1.6MB, L2-resident
__global__ __launch_bounds__(256) void kB(const float* __restrict__ h,
                                          float* __restrict__ h3, int V) {
    int v = blockIdx.x * 256 + threadIdx.x;
    if (v >= V) return;
    float hm = (v > 0) ? h[v - 1] : 0.0f;
    float h0 = h[v];
    float hp = (v + 1 < V) ? h[v + 1] : 0.0f;
    *(float4*)(h3 + (size_t)v * 4) = make_float4(hm, h0, hp, 0.0f);
}

// FUSED kC+kD+kE. One block = 16 vertices, 256 threads / 4 waves.
__global__ __launch_bounds__(256) void kF(const float* __restrict__ h3,
                                          const int* __restrict__ nb2,
                                          const float* __restrict__ w1,
                                          const float* __restrict__ b1,
                                          const float* __restrict__ wv2,
                                          const float* __restrict__ bv2,
                                          const float* __restrict__ w2t,
                                          const float* __restrict__ b2,
                                          const short* __restrict__ wBh,
                                          const short* __restrict__ wBm,
                                          const float* __restrict__ bfc,
                                          float* __restrict__ out, int V) {
    __shared__ float ys[18 * 32 * 4];    // 9216 B: (y.x,y.y,y.z,m) per (r,j);
                                         // aliased as f2s[16][68] after ph2
    __shared__ float h2s[18 * 32];       // 2304 B, rows v0-1 .. v0+16
    __shared__ float redmax[4][16];
    __shared__ float redsum[4][16];
    float* f2s = ys;                     // alias (ys dead after ph2; fenced)

    int t = threadIdx.x;
    int vbase = blockIdx.x * 16;         // V % 16 == 0

    // ---- ph1 (fused): gather h3[nb2[v,j]] + conv-of-affine y via shfl ----
    // stride 256 == 0 mod 32 -> j = lane&31 stays aligned per row group.
    {
        float w0 = wv2[0], w1_ = wv2[1], w2_ = wv2[2];
        for (int i = t; i < 18 * 32; i += 256) {
            int r = i >> 5;
            int j = i & 31;
            int v = vbase - 1 + r;
            float4 val = make_float4(0.f, 0.f, 0.f, 0.f);
            if (v >= 0 && v < V) {
                int idx = nb2[(size_t)v * 32 + j];
                val = *(const float4*)(h3 + (size_t)idx * 4);
            }
            float hmx = __shfl_up(val.x, 1, 32);
            float hmy = __shfl_up(val.y, 1, 32);
            float hmz = __shfl_up(val.z, 1, 32);
            float hpx = __shfl_down(val.x, 1, 32);
            float hpy = __shfl_down(val.y, 1, 32);
            float hpz = __shfl_down(val.z, 1, 32);
            if (j == 0)  { hmx = 0.f; hmy = 0.f; hmz = 0.f; }
            if (j == 31) { hpx = 0.f; hpy = 0.f; hpz = 0.f; }
            float4 y;
            y.x = fmaf(w0, hmx, fmaf(w1_, val.x, w2_ * hpx));
            y.y = fmaf(w0, hmy, fmaf(w1_, val.y, w2_ * hpy));
            y.z = fmaf(w0, hmz, fmaf(w1_, val.z, w2_ * hpz));
            y.w = ((j > 0) ? w0 : 0.0f) + w1_ + ((j < 31) ? w2_ : 0.0f);
            *(float4*)(ys + i * 4) = y;
        }
    }
    __syncthreads();

    // ---- ph2: h2[r][c] = mean_j relu(<y_j,u_c> + m_j*bc + b) ----
    for (int i = t; i < 18 * 32; i += 256) {
        int r = i >> 5;
        int c = i & 31;
        int v = vbase - 1 + r;
        float res = 0.0f;
        if (v >= 0 && v < V) {
            float u0 = w1[c * 3 + 0], u1 = w1[c * 3 + 1], u2 = w1[c * 3 + 2];
            float bc = b1[c];
            float b = bv2[0];
            const float* ybase = ys + r * 32 * 4;
            float s = 0.0f;
            #pragma unroll
            for (int j = 0; j < 32; ++j) {
                float4 yv = *(const float4*)(ybase + j * 4);
                float val = fmaf(yv.x, u0, fmaf(yv.y, u1,
                            fmaf(yv.z, u2, fmaf(yv.w, bc, b))));
                s += fmaxf(val, 0.0f);
            }
            res = s * (1.0f / 32.0f);
        }
        h2s[r * 32 + c] = res;
    }
    __syncthreads();   // after this, ys has no readers -> f2s alias safe

    // ---- ph3: kD einsum from h2s -> f2s[16][68] (LDS); 4 waves x 4 rows --
    {
        int o = t & 63;
        int w4 = t >> 6;      // 0..3
        int vb = w4 * 4;
        float bo = b2[o];
        float acc[4];
        #pragma unroll
        for (int m = 0; m < 4; ++m) acc[m] = bo;

        #pragma unroll
        for (int c4 = 0; c4 < 8; ++c4) {
            float4 hv[6];
            #pragma unroll
            for (int r = 0; r < 6; ++r)
                hv[r] = *(const float4*)(h2s + (vb + r) * 32 + c4 * 4);
            #pragma unroll
            for (int k = 0; k < 3; ++k) {
                #pragma unroll
                for (int cc = 0; cc < 4; ++cc) {
                    int c = c4 * 4 + cc;
                    float wv = w2t[(k * 32 + c) * 64 + o];
                    #pragma unroll
                    for (int m = 0; m < 4; ++m) {
                        float hval = (cc == 0) ? hv[m + k].x :
                                     (cc == 1) ? hv[m + k].y :
                                     (cc == 2) ? hv[m + k].z : hv[m + k].w;
                        acc[m] = fmaf(hval, wv, acc[m]);
                    }
                }
            }
        }
        #pragma unroll
        for (int m = 0; m < 4; ++m)
            f2s[(vb + m) * 68 + o] = acc[m];
    }
    __syncthreads();

    // ---- ph4: kE MFMA fc + softmax, SPLIT-K, 2-WAY bf16 split.
    //      4 waves, wave w4 owns N-quadrant w4 (8 tiles) of the 16 rows. --
    int w4 = t >> 6;         // 0..3 = N-quadrant
    int l = t & 63;
    int c16 = l & 15;
    int g = l >> 4;          // K-group / row-group
    const float* rowp = f2s + c16 * 68 + g * 8;
    const bf16x8* Bh = (const bf16x8*)wBh;
    const bf16x8* Bm = (const bf16x8*)wBm;

    f32x4 acc[8];

#define SPLIT(AH, AM, idx, x) { \
        float xx = (x); \
        unsigned short h_ = f2bf(xx); \
        float r1_ = xx - bf2f(h_); \
        AH[idx] = (short)h_; AM[idx] = (short)f2bf(r1_); }

    // ---- phase A: K = 0..31 (s=0 fragments only) ----
    {
        bf16x8 ah, am;
        float4 q0 = *(const float4*)(rowp);        // k=g*8..+3
        float4 q1 = *(const float4*)(rowp + 4);    // k=g*8+4..+7
        SPLIT(ah, am, 0, q0.x) SPLIT(ah, am, 1, q0.y)
        SPLIT(ah, am, 2, q0.z) SPLIT(ah, am, 3, q0.w)
        SPLIT(ah, am, 4, q1.x) SPLIT(ah, am, 5, q1.y)
        SPLIT(ah, am, 6, q1.z) SPLIT(ah, am, 7, q1.w)
        #pragma unroll
        for (int n8 = 0; n8 < 8; ++n8) {
            int n = w4 * 8 + n8;
            bf16x8 bh = Bh[(n * 2 + 0) * 64 + l];
            bf16x8 bm = Bm[(n * 2 + 0) * 64 + l];
            f32x4 c = {0.f, 0.f, 0.f, 0.f};
            c = __builtin_amdgcn_mfma_f32_16x16x32_bf16(ah, bh, c, 0, 0, 0);
            c = __builtin_amdgcn_mfma_f32_16x16x32_bf16(ah, bm, c, 0, 0, 0);
            c = __builtin_amdgcn_mfma_f32_16x16x32_bf16(am, bh, c, 0, 0, 0);
            acc[n8] = c;
        }
    }

    // ---- phase B: K = 32..63 (s=1 fragments), then bias ----
    {
        bf16x8 ah, am;
        float4 q2 = *(const float4*)(rowp + 32);
        float4 q3 = *(const float4*)(rowp + 36);
        SPLIT(ah, am, 0, q2.x) SPLIT(ah, am, 1, q2.y)
        SPLIT(ah, am, 2, q2.z) SPLIT(ah, am, 3, q2.w)
        SPLIT(ah, am, 4, q3.x) SPLIT(ah, am, 5, q3.y)
        SPLIT(ah, am, 6, q3.z) SPLIT(ah, am, 7, q3.w)
        #pragma unroll
        for (int n8 = 0; n8 < 8; ++n8) {
            int n = w4 * 8 + n8;
            bf16x8 bh = Bh[(n * 2 + 1) * 64 + l];
            bf16x8 bm = Bm[(n * 2 + 1) * 64 + l];
            f32x4 c = acc[n8];
            c = __builtin_amdgcn_mfma_f32_16x16x32_bf16(ah, bh, c, 0, 0, 0);
            c = __builtin_amdgcn_mfma_f32_16x16x32_bf16(ah, bm, c, 0, 0, 0);
            c = __builtin_amdgcn_mfma_f32_16x16x32_bf16(am, bh, c, 0, 0, 0);
            float bn = bfc[n * 16 + c16];
            c.x += bn; c.y += bn; c.z += bn; c.w += bn;
            acc[n8] = c;
        }
    }
#undef SPLIT

    // ---- softmax: row = g*4 + j; 16-lane reduce then 4-wave combine ----
    float m0 = -1e30f, m1 = -1e30f, m2 = -1e30f, m3 = -1e30f;
    #pragma unroll
    for (int n8 = 0; n8 < 8; ++n8) {
        m0 = fmaxf(m0, acc[n8].x); m1 = fmaxf(m1, acc[n8].y);
        m2 = fmaxf(m2, acc[n8].z); m3 = fmaxf(m3, acc[n8].w);
    }
    #pragma unroll
    for (int off = 8; off; off >>= 1) {
        m0 = fmaxf(m0, __shfl_xor(m0, off));
        m1 = fmaxf(m1, __shfl_xor(m1, off));
        m2 = fmaxf(m2, __shfl_xor(m2, off));
        m3 = fmaxf(m3, __shfl_xor(m3, off));
    }
    if (c16 == 0) {
        redmax[w4][g * 4 + 0] = m0;  redmax[w4][g * 4 + 1] = m1;
        redmax[w4][g * 4 + 2] = m2;  redmax[w4][g * 4 + 3] = m3;
    }
    __syncthreads();
#define GMAX(r) fmaxf(fmaxf(redmax[0][r], redmax[1][r]), \
                      fmaxf(redmax[2][r], redmax[3][r]))
    float g0 = GMAX(g * 4 + 0), g1 = GMAX(g * 4 + 1);
    float g2 = GMAX(g * 4 + 2), g3 = GMAX(g * 4 + 3);
#undef GMAX

    float s0 = 0.f, s1 = 0.f, s2 = 0.f, s3 = 0.f;
    #pragma unroll
    for (int n8 = 0; n8 < 8; ++n8) {
        acc[n8].x = __expf(acc[n8].x - g0); s0 += acc[n8].x;
        acc[n8].y = __expf(acc[n8].y - g1); s1 += acc[n8].y;
        acc[n8].z = __expf(acc[n8].z - g2); s2 += acc[n8].z;
        acc[n8].w = __expf(acc[n8].w - g3); s3 += acc[n8].w;
    }
    #pragma unroll
    for (int off = 8; off; off >>= 1) {
        s0 += __shfl_xor(s0, off); s1 += __shfl_xor(s1, off);
        s2 += __shfl_xor(s2, off); s3 += __shfl_xor(s3, off);
    }
    if (c16 == 0) {
        redsum[w4][g * 4 + 0] = s0;  redsum[w4][g * 4 + 1] = s1;
        redsum[w4][g * 4 + 2] = s2;  redsum[w4][g * 4 + 3] = s3;
    }
    __syncthreads();
#define GSUM(r) (redsum[0][r] + redsum[1][r] + redsum[2][r] + redsum[3][r])
    float i0 = 1.0f / GSUM(g * 4 + 0), i1 = 1.0f / GSUM(g * 4 + 1);
    float i2 = 1.0f / GSUM(g * 4 + 2), i3 = 1.0f / GSUM(g * 4 + 3);
#undef GSUM

    // ---- store: out[(vbase+g*4+j)*512 + n*16 + c16] ----
    #pragma unroll
    for (int n8 = 0; n8 < 8; ++n8) {
        int n = w4 * 8 + n8;
        float* op = out + (size_t)(vbase + g * 4) * 512 + n * 16 + c16;
        __builtin_nontemporal_store(acc[n8].x * i0, op);
        __builtin_nontemporal_store(acc[n8].y * i1, op + 512);
        __builtin_nontemporal_store(acc[n8].z * i2, op + 1024);
        __builtin_nontemporal_store(acc[n8].w * i3, op + 1536);
    }
}

extern "C" void kernel_launch(void* const* d_in, const int* in_sizes, int n_in,
                              void* d_out, int out_size, void* d_ws, size_t ws_size,
                              hipStream_t stream) {
    (void)n_in; (void)out_size; (void)ws_size;
    const float* vp  = (const float*)d_in[0];
    const int*   nb1 = (const int*)d_in[1];
    const int*   nb2 = (const int*)d_in[2];
    const float* wv1 = (const float*)d_in[3];
    const float* bv1 = (const float*)d_in[4];
    const float* w1  = (const float*)d_in[5];
    const float* b1  = (const float*)d_in[6];
    const float* wv2 = (const float*)d_in[7];
    const float* bv2 = (const float*)d_in[8];
    const float* w2  = (const float*)d_in[9];
    const float* b2  = (const float*)d_in[10];
    const float* wfc = (const float*)d_in[11];
    const float* bfc = (const float*)d_in[12];
    float* out = (float*)d_out;
    const int V = in_sizes[0];

    float* ws = (float*)d_ws;
    size_t off = 0;
    float* h    = ws + off; off += (size_t)V;
    float* h3   = ws + off; off += (size_t)V * 4;   // 16B aligned
    float* w2t  = ws + off; off += 3 * 32 * 64;
    short* wBh  = (short*)(ws + off); off += 32768 / 2;   // 32768 shorts
    short* wBm  = (short*)(ws + off); off += 32768 / 2;

    k_prep<<<(32768 + 6144 + 255) / 256, 256, 0, stream>>>(wfc, w2, wBh, wBm, w2t);
    kA<<<(V + 255) / 256, 256, 0, stream>>>(vp, nb1, wv1, bv1, h, V);
    kB<<<(V + 255) / 256, 256, 0, stream>>>(h, h3, V);
    kF<<<V / 16, 256, 0, stream>>>(h3, nb2, w1, b1, wv2, bv2, w2t, b2,
                                   wBh, wBm, bfc, out, V);
}

// Round 24
// 333.837 us; speedup vs baseline: 1.2538x; 1.0195x over previous
//
#include <hip/hip_runtime.h>

// ---------------------------------------------------------------------------
// Pipeline:
//  k_prep : wfc[512,64] -> wB{h,m} (2-way bf16 B-frags for ph4 fc)
//           w2[64,32,3] -> wB2{h,m} (2-way bf16 B-frags for ph3 einsum)
//  kA     : h[v] = mean_j relu(conv3_j(vp[nb1[v,:]]))               [V]
//  kB     : h3[v] = (h[v-1], h[v], h[v+1], 0)                       [V,4]
//  kF     : FUSED kC+kD+kE per 16-vertex block, 256 THREADS / 4 WAVES
//
// R27 = R26 + ph3 MOVED TO THE MATRIX PIPE. R26 counters: kF 128.7us,
// VALU 52% / MFMA 6.5% / HBM 26% -- no pipe saturated, VALU issue is the
// cost, and ph3 (~500 ops/thread) is the largest VALU block. But ph3 IS
// a GEMM: f2[16x64] = A[16x96] x B[96x64] + b2, A[v][(k,c)]=h2[v-1+k][c].
// Per wave (one 16-col N-tile): 3 k-shifts x 3 products (2-way split) =
// 9 MFMAs + ~150 VALU replacing ~500. B pre-split in k_prep (w2t gone).
// h2s padded to stride 36 (16B-aligned; 16-way bank conflict -> free
// 2-way). f2 error ~2^-18 rel -> output ~1e-8 (same math as R19's fc).
// Verify: kF -> ~105-115; absmax may tick; revert ph3 if harness fails.
// ---------------------------------------------------------------------------

typedef short bf16x8 __attribute__((ext_vector_type(8)));
typedef float f32x4 __attribute__((ext_vector_type(4)));

__device__ inline unsigned short f2bf(float x) {
    unsigned u = __float_as_uint(x);
    unsigned r = (u + 0x7FFFu + ((u >> 16) & 1u)) >> 16;
    return (unsigned short)r;
}
__device__ inline float bf2f(unsigned short b) {
    return __uint_as_float(((unsigned)b) << 16);
}

// k_prep: wfc -> 2-way bf16 fc-B-frags; w2 -> 2-way bf16 einsum-B-frags.
// wB2 layout [k][n][lane][j]: B_k[c][o], c=(l>>4)*8+j, o=n*16+(l&15),
// value = w2[o*96 + c*3 + k].
__global__ __launch_bounds__(256) void k_prep(const float* __restrict__ wfc,
                                              const float* __restrict__ w2,
                                              short* __restrict__ wBh,
                                              short* __restrict__ wBm,
                                              short* __restrict__ wB2h,
                                              short* __restrict__ wB2m) {
    int t = blockIdx.x * 256 + threadIdx.x;
    if (t < 32768) {
        int j = t & 7;
        int l = (t >> 3) & 63;
        int s = (t >> 9) & 1;
        int n = t >> 10;
        int col = n * 16 + (l & 15);
        int k = s * 32 + (l >> 4) * 8 + j;
        float v = wfc[col * 64 + k];
        unsigned short h = f2bf(v);
        float r1 = v - bf2f(h);
        wBh[t] = (short)h;
        wBm[t] = (short)f2bf(r1);
    } else if (t < 32768 + 6144) {
        int i = t - 32768;
        int j = i & 7;
        int l = (i >> 3) & 63;
        int n = (i >> 9) & 3;
        int k = i >> 11;                 // 0..2
        int c = (l >> 4) * 8 + j;
        int o = n * 16 + (l & 15);
        float v = w2[o * 96 + c * 3 + k];
        unsigned short h = f2bf(v);
        float r1 = v - bf2f(h);
        wB2h[i] = (short)h;
        wB2m[i] = (short)f2bf(r1);
    }
}

// conv1: one vertex per thread, 32 independent vp gathers in flight.
__global__ __launch_bounds__(256) void kA(const float* __restrict__ vp,
                                          const int* __restrict__ nb1,
                                          const float* __restrict__ wv1,
                                          const float* __restrict__ bv1,
                                          float* __restrict__ h, int V) {
    int v = blockIdx.x * 256 + threadIdx.x;
    if (v >= V) return;
    const int* nb = nb1 + (size_t)v * 32;

    int idx[32];
    #pragma unroll
    for (int q = 0; q < 8; ++q) {
        int4 t4 = *(const int4*)(nb + q * 4);
        idx[q * 4 + 0] = t4.x;
        idx[q * 4 + 1] = t4.y;
        idx[q * 4 + 2] = t4.z;
        idx[q * 4 + 3] = t4.w;
    }
    float x[32];
    #pragma unroll
    for (int j = 0; j < 32; ++j)
        x[j] = vp[idx[j]];

    float w0 = wv1[0], w1_ = wv1[1], w2_ = wv1[2], b = bv1[0];
    float s = 0.0f;
    #pragma unroll
    for (int j = 0; j < 32; ++j) {
        float pv = (j > 0)  ? x[j - 1] : 0.0f;
        float nx = (j < 31) ? x[j + 1] : 0.0f;
        float cv = fmaf(w0, pv, fmaf(w1_, x[j], fmaf(w2_, nx, b)));
        s += fmaxf(cv, 0.0f);
    }
    h[v] = s * (1.0f / 32.0f);
}

// h3 builder: h3[v] = (h[v-1], h[v], h[v+1], 0) -- 1.6MB, L2-resident
__global__ __launch_bounds__(256) void kB(const float* __restrict__ h,
                                          float* __restrict__ h3, int V) {
    int v = blockIdx.x * 256 + threadIdx.x;
    if (v >= V) return;
    float hm = (v > 0) ? h[v - 1] : 0.0f;
    float h0 = h[v];
    float hp = (v + 1 < V) ? h[v + 1] : 0.0f;
    *(float4*)(h3 + (size_t)v * 4) = make_float4(hm, h0, hp, 0.0f);
}

// FUSED kC+kD+kE. One block = 16 vertices, 256 threads / 4 waves.
__global__ __launch_bounds__(256) void kF(const float* __restrict__ h3,
                                          const int* __restrict__ nb2,
                                          const float* __restrict__ w1,
                                          const float* __restrict__ b1,
                                          const float* __restrict__ wv2,
                                          const float* __restrict__ bv2,
                                          const float* __restrict__ b2,
                                          const short* __restrict__ wBh,
                                          const short* __restrict__ wBm,
                                          const short* __restrict__ wB2h,
                                          const short* __restrict__ wB2m,
                                          const float* __restrict__ bfc,
                                          float* __restrict__ out, int V) {
    __shared__ float ys[18 * 32 * 4];    // 9216 B; aliased as f2s[16][68]
    __shared__ float h2s[18 * 36];       // 2592 B, stride-36 pad (16B-aligned)
    __shared__ float redmax[4][16];
    __shared__ float redsum[4][16];
    float* f2s = ys;                     // alias (ys dead after ph2; fenced)

    int t = threadIdx.x;
    int vbase = blockIdx.x * 16;         // V % 16 == 0

    // ---- ph1 (fused): gather h3[nb2[v,j]] + conv-of-affine y via shfl ----
    {
        float w0 = wv2[0], w1_ = wv2[1], w2_ = wv2[2];
        for (int i = t; i < 18 * 32; i += 256) {
            int r = i >> 5;
            int j = i & 31;
            int v = vbase - 1 + r;
            float4 val = make_float4(0.f, 0.f, 0.f, 0.f);
            if (v >= 0 && v < V) {
                int idx = nb2[(size_t)v * 32 + j];
                val = *(const float4*)(h3 + (size_t)idx * 4);
            }
            float hmx = __shfl_up(val.x, 1, 32);
            float hmy = __shfl_up(val.y, 1, 32);
            float hmz = __shfl_up(val.z, 1, 32);
            float hpx = __shfl_down(val.x, 1, 32);
            float hpy = __shfl_down(val.y, 1, 32);
            float hpz = __shfl_down(val.z, 1, 32);
            if (j == 0)  { hmx = 0.f; hmy = 0.f; hmz = 0.f; }
            if (j == 31) { hpx = 0.f; hpy = 0.f; hpz = 0.f; }
            float4 y;
            y.x = fmaf(w0, hmx, fmaf(w1_, val.x, w2_ * hpx));
            y.y = fmaf(w0, hmy, fmaf(w1_, val.y, w2_ * hpy));
            y.z = fmaf(w0, hmz, fmaf(w1_, val.z, w2_ * hpz));
            y.w = ((j > 0) ? w0 : 0.0f) + w1_ + ((j < 31) ? w2_ : 0.0f);
            *(float4*)(ys + i * 4) = y;
        }
    }
    __syncthreads();

    // ---- ph2: h2[r][c] = mean_j relu(<y_j,u_c> + m_j*bc + b) ----
    for (int i = t; i < 18 * 32; i += 256) {
        int r = i >> 5;
        int c = i & 31;
        int v = vbase - 1 + r;
        float res = 0.0f;
        if (v >= 0 && v < V) {
            float u0 = w1[c * 3 + 0], u1 = w1[c * 3 + 1], u2 = w1[c * 3 + 2];
            float bc = b1[c];
            float b = bv2[0];
            const float* ybase = ys + r * 32 * 4;
            float s = 0.0f;
            #pragma unroll
            for (int j = 0; j < 32; ++j) {
                float4 yv = *(const float4*)(ybase + j * 4);
                float val = fmaf(yv.x, u0, fmaf(yv.y, u1,
                            fmaf(yv.z, u2, fmaf(yv.w, bc, b))));
                s += fmaxf(val, 0.0f);
            }
            res = s * (1.0f / 32.0f);
        }
        h2s[r * 36 + c] = res;
    }
    __syncthreads();   // ys dead after this (f2s alias safe); h2s ready

#define SPLIT(AH, AM, idx, x) { \
        float xx = (x); \
        unsigned short h_ = f2bf(xx); \
        float r1_ = xx - bf2f(h_); \
        AH[idx] = (short)h_; AM[idx] = (short)f2bf(r1_); }

    int w4 = t >> 6;         // 0..3 = N-tile / N-quadrant
    int l = t & 63;
    int c16 = l & 15;
    int g = l >> 4;          // K-group / row-group

    // ---- ph3 (MFMA): f2[16x64] = sum_k A_k[16x32] x B_k[32x16] + b2 ----
    // A_k[v][c] = h2s[(v+k)*36 + c]; lane: v=c16, c=g*8+j (8 contiguous).
    {
        const bf16x8* B2h = (const bf16x8*)wB2h;
        const bf16x8* B2m = (const bf16x8*)wB2m;
        f32x4 acc3 = {0.f, 0.f, 0.f, 0.f};
        #pragma unroll
        for (int k = 0; k < 3; ++k) {
            const float* ap = h2s + (c16 + k) * 36 + g * 8;
            float4 a0 = *(const float4*)(ap);
            float4 a1 = *(const float4*)(ap + 4);
            bf16x8 ah, am;
            SPLIT(ah, am, 0, a0.x) SPLIT(ah, am, 1, a0.y)
            SPLIT(ah, am, 2, a0.z) SPLIT(ah, am, 3, a0.w)
            SPLIT(ah, am, 4, a1.x) SPLIT(ah, am, 5, a1.y)
            SPLIT(ah, am, 6, a1.z) SPLIT(ah, am, 7, a1.w)
            bf16x8 bh = B2h[(k * 4 + w4) * 64 + l];
            bf16x8 bm = B2m[(k * 4 + w4) * 64 + l];
            acc3 = __builtin_amdgcn_mfma_f32_16x16x32_bf16(ah, bh, acc3, 0, 0, 0);
            acc3 = __builtin_amdgcn_mfma_f32_16x16x32_bf16(ah, bm, acc3, 0, 0, 0);
            acc3 = __builtin_amdgcn_mfma_f32_16x16x32_bf16(am, bh, acc3, 0, 0, 0);
        }
        // D: col=c16 -> o = w4*16+c16; row = g*4+r -> vertex row
        float bo = b2[w4 * 16 + c16];
        #pragma unroll
        for (int r = 0; r < 4; ++r)
            f2s[(g * 4 + r) * 68 + w4 * 16 + c16] = acc3[r] + bo;
    }
    __syncthreads();

    // ---- ph4: kE MFMA fc + softmax, SPLIT-K, 2-WAY bf16 split. ----
    const float* rowp = f2s + c16 * 68 + g * 8;
    const bf16x8* Bh = (const bf16x8*)wBh;
    const bf16x8* Bm = (const bf16x8*)wBm;

    f32x4 acc[8];

    // ---- phase A: K = 0..31 (s=0 fragments only) ----
    {
        bf16x8 ah, am;
        float4 q0 = *(const float4*)(rowp);        // k=g*8..+3
        float4 q1 = *(const float4*)(rowp + 4);    // k=g*8+4..+7
        SPLIT(ah, am, 0, q0.x) SPLIT(ah, am, 1, q0.y)
        SPLIT(ah, am, 2, q0.z) SPLIT(ah, am, 3, q0.w)
        SPLIT(ah, am, 4, q1.x) SPLIT(ah, am, 5, q1.y)
        SPLIT(ah, am, 6, q1.z) SPLIT(ah, am, 7, q1.w)
        #pragma unroll
        for (int n8 = 0; n8 < 8; ++n8) {
            int n = w4 * 8 + n8;
            bf16x8 bh = Bh[(n * 2 + 0) * 64 + l];
            bf16x8 bm = Bm[(n * 2 + 0) * 64 + l];
            f32x4 c = {0.f, 0.f, 0.f, 0.f};
            c = __builtin_amdgcn_mfma_f32_16x16x32_bf16(ah, bh, c, 0, 0, 0);
            c = __builtin_amdgcn_mfma_f32_16x16x32_bf16(ah, bm, c, 0, 0, 0);
            c = __builtin_amdgcn_mfma_f32_16x16x32_bf16(am, bh, c, 0, 0, 0);
            acc[n8] = c;
        }
    }

    // ---- phase B: K = 32..63 (s=1 fragments), then bias ----
    {
        bf16x8 ah, am;
        float4 q2 = *(const float4*)(rowp + 32);
        float4 q3 = *(const float4*)(rowp + 36);
        SPLIT(ah, am, 0, q2.x) SPLIT(ah, am, 1, q2.y)
        SPLIT(ah, am, 2, q2.z) SPLIT(ah, am, 3, q2.w)
        SPLIT(ah, am, 4, q3.x) SPLIT(ah, am, 5, q3.y)
        SPLIT(ah, am, 6, q3.z) SPLIT(ah, am, 7, q3.w)
        #pragma unroll
        for (int n8 = 0; n8 < 8; ++n8) {
            int n = w4 * 8 + n8;
            bf16x8 bh = Bh[(n * 2 + 1) * 64 + l];
            bf16x8 bm = Bm[(n * 2 + 1) * 64 + l];
            f32x4 c = acc[n8];
            c = __builtin_amdgcn_mfma_f32_16x16x32_bf16(ah, bh, c, 0, 0, 0);
            c = __builtin_amdgcn_mfma_f32_16x16x32_bf16(ah, bm, c, 0, 0, 0);
            c = __builtin_amdgcn_mfma_f32_16x16x32_bf16(am, bh, c, 0, 0, 0);
            float bn = bfc[n * 16 + c16];
            c.x += bn; c.y += bn; c.z += bn; c.w += bn;
            acc[n8] = c;
        }
    }
#undef SPLIT

    // ---- softmax: row = g*4 + j; 16-lane reduce then 4-wave combine ----
    float m0 = -1e30f, m1 = -1e30f, m2 = -1e30f, m3 = -1e30f;
    #pragma unroll
    for (int n8 = 0; n8 < 8; ++n8) {
        m0 = fmaxf(m0, acc[n8].x); m1 = fmaxf(m1, acc[n8].y);
        m2 = fmaxf(m2, acc[n8].z); m3 = fmaxf(m3, acc[n8].w);
    }
    #pragma unroll
    for (int off = 8; off; off >>= 1) {
        m0 = fmaxf(m0, __shfl_xor(m0, off));
        m1 = fmaxf(m1, __shfl_xor(m1, off));
        m2 = fmaxf(m2, __shfl_xor(m2, off));
        m3 = fmaxf(m3, __shfl_xor(m3, off));
    }
    if (c16 == 0) {
        redmax[w4][g * 4 + 0] = m0;  redmax[w4][g * 4 + 1] = m1;
        redmax[w4][g * 4 + 2] = m2;  redmax[w4][g * 4 + 3] = m3;
    }
    __syncthreads();
#define GMAX(r) fmaxf(fmaxf(redmax[0][r], redmax[1][r]), \
                      fmaxf(redmax[2][r], redmax[3][r]))
    float g0 = GMAX(g * 4 + 0), g1 = GMAX(g * 4 + 1);
    float g2 = GMAX(g * 4 + 2), g3 = GMAX(g * 4 + 3);
#undef GMAX

    float s0 = 0.f, s1 = 0.f, s2 = 0.f, s3 = 0.f;
    #pragma unroll
    for (int n8 = 0; n8 < 8; ++n8) {
        acc[n8].x = __expf(acc[n8].x - g0); s0 += acc[n8].x;
        acc[n8].y = __expf(acc[n8].y - g1); s1 += acc[n8].y;
        acc[n8].z = __expf(acc[n8].z - g2); s2 += acc[n8].z;
        acc[n8].w = __expf(acc[n8].w - g3); s3 += acc[n8].w;
    }
    #pragma unroll
    for (int off = 8; off; off >>= 1) {
        s0 += __shfl_xor(s0, off); s1 += __shfl_xor(s1, off);
        s2 += __shfl_xor(s2, off); s3 += __shfl_xor(s3, off);
    }
    if (c16 == 0) {
        redsum[w4][g * 4 + 0] = s0;  redsum[w4][g * 4 + 1] = s1;
        redsum[w4][g * 4 + 2] = s2;  redsum[w4][g * 4 + 3] = s3;
    }
    __syncthreads();
#define GSUM(r) (redsum[0][r] + redsum[1][r] + redsum[2][r] + redsum[3][r])
    float i0 = 1.0f / GSUM(g * 4 + 0), i1 = 1.0f / GSUM(g * 4 + 1);
    float i2 = 1.0f / GSUM(g * 4 + 2), i3 = 1.0f / GSUM(g * 4 + 3);
#undef GSUM

    // ---- store: out[(vbase+g*4+j)*512 + n*16 + c16] ----
    #pragma unroll
    for (int n8 = 0; n8 < 8; ++n8) {
        int n = w4 * 8 + n8;
        float* op = out + (size_t)(vbase + g * 4) * 512 + n * 16 + c16;
        __builtin_nontemporal_store(acc[n8].x * i0, op);
        __builtin_nontemporal_store(acc[n8].y * i1, op + 512);
        __builtin_nontemporal_store(acc[n8].z * i2, op + 1024);
        __builtin_nontemporal_store(acc[n8].w * i3, op + 1536);
    }
}

extern "C" void kernel_launch(void* const* d_in, const int* in_sizes, int n_in,
                              void* d_out, int out_size, void* d_ws, size_t ws_size,
                              hipStream_t stream) {
    (void)n_in; (void)out_size; (void)ws_size;
    const float* vp  = (const float*)d_in[0];
    const int*   nb1 = (const int*)d_in[1];
    const int*   nb2 = (const int*)d_in[2];
    const float* wv1 = (const float*)d_in[3];
    const float* bv1 = (const float*)d_in[4];
    const float* w1  = (const float*)d_in[5];
    const float* b1  = (const float*)d_in[6];
    const float* wv2 = (const float*)d_in[7];
    const float* bv2 = (const float*)d_in[8];
    const float* w2  = (const float*)d_in[9];
    const float* b2  = (const float*)d_in[10];
    const float* wfc = (const float*)d_in[11];
    const float* bfc = (const float*)d_in[12];
    float* out = (float*)d_out;
    const int V = in_sizes[0];

    float* ws = (float*)d_ws;
    size_t off = 0;
    float* h    = ws + off; off += (size_t)V;
    float* h3   = ws + off; off += (size_t)V * 4;   // 16B aligned
    short* wBh  = (short*)(ws + off); off += 32768 / 2;   // 32768 shorts
    short* wBm  = (short*)(ws + off); off += 32768 / 2;
    short* wB2h = (short*)(ws + off); off += 6144 / 2;    // 6144 shorts
    short* wB2m = (short*)(ws + off); off += 6144 / 2;

    k_prep<<<(32768 + 6144 + 255) / 256, 256, 0, stream>>>(wfc, w2, wBh, wBm, wB2h, wB2m);
    kA<<<(V + 255) / 256, 256, 0, stream>>>(vp, nb1, wv1, bv1, h, V);
    kB<<<(V + 255) / 256, 256, 0, stream>>>(h, h3, V);
    kF<<<V / 16, 256, 0, stream>>>(h3, nb2, w1, b1, wv2, bv2, b2,
                                   wBh, wBm, wB2h, wB2m, bfc, out, V);
}

// Round 25
// 330.346 us; speedup vs baseline: 1.2670x; 1.0106x over previous
//
#include <hip/hip_runtime.h>

// ---------------------------------------------------------------------------
// Pipeline:
//  kAP    : fused kA (conv1 per-thread gather) + k_prep (wfc/w2 bf16 frags)
//  kB     : h3[v] = (h[v-1], h[v], h[v+1], 0)                       [V,4]
//  kF     : FUSED kC+kD+kE per 16-vertex block, 256 THREADS / 4 WAVES
//
// R28 = R27 + two VALU/launch cuts:
//  1) f2 handed ph3->ph4 PRE-SPLIT: ph3 epilogue splits its 4 outputs once
//     (+28 ops) into two u16 LDS planes f2h/f2m[16][72] (144B rows, 16B
//     aligned); ph4's A-frags become two direct b128 LDS loads -- the 16
//     re-SPLITs (~90 ops/thread) deleted. Same split values -> bit-identical,
//     absmax must stay 1.525879e-05.
//  2) k_prep fused into kA's launch (independent work, combined grid) --
//     one fewer launch gap.
// Verify: total 333.8 -> ~324-330; if <3us, declare practical plateau.
// ---------------------------------------------------------------------------

typedef short bf16x8 __attribute__((ext_vector_type(8)));
typedef float f32x4 __attribute__((ext_vector_type(4)));

__device__ inline unsigned short f2bf(float x) {
    unsigned u = __float_as_uint(x);
    unsigned r = (u + 0x7FFFu + ((u >> 16) & 1u)) >> 16;
    return (unsigned short)r;
}
__device__ inline float bf2f(unsigned short b) {
    return __uint_as_float(((unsigned)b) << 16);
}

// kAP: blocks [0,nA) = conv1; blocks [nA,..) = weight prep.
__global__ __launch_bounds__(256) void kAP(const float* __restrict__ vp,
                                           const int* __restrict__ nb1,
                                           const float* __restrict__ wv1,
                                           const float* __restrict__ bv1,
                                           float* __restrict__ h,
                                           const float* __restrict__ wfc,
                                           const float* __restrict__ w2,
                                           short* __restrict__ wBh,
                                           short* __restrict__ wBm,
                                           short* __restrict__ wB2h,
                                           short* __restrict__ wB2m,
                                           int V, int nA) {
    if ((int)blockIdx.x < nA) {
        int v = blockIdx.x * 256 + threadIdx.x;
        if (v >= V) return;
        const int* nb = nb1 + (size_t)v * 32;

        int idx[32];
        #pragma unroll
        for (int q = 0; q < 8; ++q) {
            int4 t4 = *(const int4*)(nb + q * 4);
            idx[q * 4 + 0] = t4.x;
            idx[q * 4 + 1] = t4.y;
            idx[q * 4 + 2] = t4.z;
            idx[q * 4 + 3] = t4.w;
        }
        float x[32];
        #pragma unroll
        for (int j = 0; j < 32; ++j)
            x[j] = vp[idx[j]];

        float w0 = wv1[0], w1_ = wv1[1], w2_ = wv1[2], b = bv1[0];
        float s = 0.0f;
        #pragma unroll
        for (int j = 0; j < 32; ++j) {
            float pv = (j > 0)  ? x[j - 1] : 0.0f;
            float nx = (j < 31) ? x[j + 1] : 0.0f;
            float cv = fmaf(w0, pv, fmaf(w1_, x[j], fmaf(w2_, nx, b)));
            s += fmaxf(cv, 0.0f);
        }
        h[v] = s * (1.0f / 32.0f);
    } else {
        int t = (blockIdx.x - nA) * 256 + threadIdx.x;
        if (t < 32768) {
            int j = t & 7;
            int l = (t >> 3) & 63;
            int s = (t >> 9) & 1;
            int n = t >> 10;
            int col = n * 16 + (l & 15);
            int k = s * 32 + (l >> 4) * 8 + j;
            float v = wfc[col * 64 + k];
            unsigned short hh = f2bf(v);
            float r1 = v - bf2f(hh);
            wBh[t] = (short)hh;
            wBm[t] = (short)f2bf(r1);
        } else if (t < 32768 + 6144) {
            int i = t - 32768;
            int j = i & 7;
            int l = (i >> 3) & 63;
            int n = (i >> 9) & 3;
            int k = i >> 11;                 // 0..2
            int c = (l >> 4) * 8 + j;
            int o = n * 16 + (l & 15);
            float v = w2[o * 96 + c * 3 + k];
            unsigned short hh = f2bf(v);
            float r1 = v - bf2f(hh);
            wB2h[i] = (short)hh;
            wB2m[i] = (short)f2bf(r1);
        }
    }
}

// h3 builder: h3[v] = (h[v-1], h[v], h[v+1], 0) -- 1.6MB, L2-resident
__global__ __launch_bounds__(256) void kB(const float* __restrict__ h,
                                          float* __restrict__ h3, int V) {
    int v = blockIdx.x * 256 + threadIdx.x;
    if (v >= V) return;
    float hm = (v > 0) ? h[v - 1] : 0.0f;
    float h0 = h[v];
    float hp = (v + 1 < V) ? h[v + 1] : 0.0f;
    *(float4*)(h3 + (size_t)v * 4) = make_float4(hm, h0, hp, 0.0f);
}

// FUSED kC+kD+kE. One block = 16 vertices, 256 threads / 4 waves.
__global__ __launch_bounds__(256) void kF(const float* __restrict__ h3,
                                          const int* __restrict__ nb2,
                                          const float* __restrict__ w1,
                                          const float* __restrict__ b1,
                                          const float* __restrict__ wv2,
                                          const float* __restrict__ bv2,
                                          const float* __restrict__ b2,
                                          const short* __restrict__ wBh,
                                          const short* __restrict__ wBm,
                                          const short* __restrict__ wB2h,
                                          const short* __restrict__ wB2m,
                                          const float* __restrict__ bfc,
                                          float* __restrict__ out, int V) {
    __shared__ float ys[18 * 32 * 4];    // 9216 B; aliased as f2h/f2m planes
    __shared__ float h2s[18 * 36];       // 2592 B, stride-36 pad
    __shared__ float redmax[4][16];
    __shared__ float redsum[4][16];
    // post-ph2 alias: two u16 planes [16][72] (144B rows, 16B-aligned)
    unsigned short* f2h = (unsigned short*)ys;           // 16*72 u16 = 2304 B
    unsigned short* f2m = (unsigned short*)ys + 16 * 72; // next 2304 B

    int t = threadIdx.x;
    int vbase = blockIdx.x * 16;         // V % 16 == 0

    // ---- ph1 (fused): gather h3[nb2[v,j]] + conv-of-affine y via shfl ----
    {
        float w0 = wv2[0], w1_ = wv2[1], w2_ = wv2[2];
        for (int i = t; i < 18 * 32; i += 256) {
            int r = i >> 5;
            int j = i & 31;
            int v = vbase - 1 + r;
            float4 val = make_float4(0.f, 0.f, 0.f, 0.f);
            if (v >= 0 && v < V) {
                int idx = nb2[(size_t)v * 32 + j];
                val = *(const float4*)(h3 + (size_t)idx * 4);
            }
            float hmx = __shfl_up(val.x, 1, 32);
            float hmy = __shfl_up(val.y, 1, 32);
            float hmz = __shfl_up(val.z, 1, 32);
            float hpx = __shfl_down(val.x, 1, 32);
            float hpy = __shfl_down(val.y, 1, 32);
            float hpz = __shfl_down(val.z, 1, 32);
            if (j == 0)  { hmx = 0.f; hmy = 0.f; hmz = 0.f; }
            if (j == 31) { hpx = 0.f; hpy = 0.f; hpz = 0.f; }
            float4 y;
            y.x = fmaf(w0, hmx, fmaf(w1_, val.x, w2_ * hpx));
            y.y = fmaf(w0, hmy, fmaf(w1_, val.y, w2_ * hpy));
            y.z = fmaf(w0, hmz, fmaf(w1_, val.z, w2_ * hpz));
            y.w = ((j > 0) ? w0 : 0.0f) + w1_ + ((j < 31) ? w2_ : 0.0f);
            *(float4*)(ys + i * 4) = y;
        }
    }
    __syncthreads();

    // ---- ph2: h2[r][c] = mean_j relu(<y_j,u_c> + m_j*bc + b) ----
    for (int i = t; i < 18 * 32; i += 256) {
        int r = i >> 5;
        int c = i & 31;
        int v = vbase - 1 + r;
        float res = 0.0f;
        if (v >= 0 && v < V) {
            float u0 = w1[c * 3 + 0], u1 = w1[c * 3 + 1], u2 = w1[c * 3 + 2];
            float bc = b1[c];
            float b = bv2[0];
            const float* ybase = ys + r * 32 * 4;
            float s = 0.0f;
            #pragma unroll
            for (int j = 0; j < 32; ++j) {
                float4 yv = *(const float4*)(ybase + j * 4);
                float val = fmaf(yv.x, u0, fmaf(yv.y, u1,
                            fmaf(yv.z, u2, fmaf(yv.w, bc, b))));
                s += fmaxf(val, 0.0f);
            }
            res = s * (1.0f / 32.0f);
        }
        h2s[r * 36 + c] = res;
    }
    __syncthreads();   // ys dead after this (plane alias safe); h2s ready

#define SPLIT(AH, AM, idx, x) { \
        float xx = (x); \
        unsigned short h_ = f2bf(xx); \
        float r1_ = xx - bf2f(h_); \
        AH[idx] = (short)h_; AM[idx] = (short)f2bf(r1_); }

    int w4 = t >> 6;         // 0..3 = N-tile / N-quadrant
    int l = t & 63;
    int c16 = l & 15;
    int g = l >> 4;          // K-group / row-group

    // ---- ph3 (MFMA): f2[16x64] = sum_k A_k[16x32] x B_k[32x16] + b2;
    //      epilogue stores PRE-SPLIT bf16 hi/mid planes for ph4 ----
    {
        const bf16x8* B2h = (const bf16x8*)wB2h;
        const bf16x8* B2m = (const bf16x8*)wB2m;
        f32x4 acc3 = {0.f, 0.f, 0.f, 0.f};
        #pragma unroll
        for (int k = 0; k < 3; ++k) {
            const float* ap = h2s + (c16 + k) * 36 + g * 8;
            float4 a0 = *(const float4*)(ap);
            float4 a1 = *(const float4*)(ap + 4);
            bf16x8 ah, am;
            SPLIT(ah, am, 0, a0.x) SPLIT(ah, am, 1, a0.y)
            SPLIT(ah, am, 2, a0.z) SPLIT(ah, am, 3, a0.w)
            SPLIT(ah, am, 4, a1.x) SPLIT(ah, am, 5, a1.y)
            SPLIT(ah, am, 6, a1.z) SPLIT(ah, am, 7, a1.w)
            bf16x8 bh = B2h[(k * 4 + w4) * 64 + l];
            bf16x8 bm = B2m[(k * 4 + w4) * 64 + l];
            acc3 = __builtin_amdgcn_mfma_f32_16x16x32_bf16(ah, bh, acc3, 0, 0, 0);
            acc3 = __builtin_amdgcn_mfma_f32_16x16x32_bf16(ah, bm, acc3, 0, 0, 0);
            acc3 = __builtin_amdgcn_mfma_f32_16x16x32_bf16(am, bh, acc3, 0, 0, 0);
        }
        // D: col=c16 -> o = w4*16+c16; row = g*4+r. Split once, store planes.
        float bo = b2[w4 * 16 + c16];
        #pragma unroll
        for (int r = 0; r < 4; ++r) {
            float v = acc3[r] + bo;
            unsigned short h_ = f2bf(v);
            float r1_ = v - bf2f(h_);
            int o = w4 * 16 + c16;
            // plane index: [row=vertex within 16][k=o? no] -- plane is
            // [vertex row][fc-K] = f2[v][o]: row v = g*4+r, col = o
            f2h[(g * 4 + r) * 72 + o] = h_;
            f2m[(g * 4 + r) * 72 + o] = f2bf(r1_);
        }
    }
    __syncthreads();

    // ---- ph4: kE MFMA fc + softmax, SPLIT-K. A-frags load PRE-SPLIT ----
    // lane: vertex row = c16, k = g*8+j (phase A), +32 (phase B)
    const unsigned short* rowh = f2h + c16 * 72 + g * 8;
    const unsigned short* rowm = f2m + c16 * 72 + g * 8;
    const bf16x8* Bh = (const bf16x8*)wBh;
    const bf16x8* Bm = (const bf16x8*)wBm;

    f32x4 acc[8];

    // ---- phase A: K = 0..31 ----
    {
        bf16x8 ah = *(const bf16x8*)(rowh);
        bf16x8 am = *(const bf16x8*)(rowm);
        #pragma unroll
        for (int n8 = 0; n8 < 8; ++n8) {
            int n = w4 * 8 + n8;
            bf16x8 bh = Bh[(n * 2 + 0) * 64 + l];
            bf16x8 bm = Bm[(n * 2 + 0) * 64 + l];
            f32x4 c = {0.f, 0.f, 0.f, 0.f};
            c = __builtin_amdgcn_mfma_f32_16x16x32_bf16(ah, bh, c, 0, 0, 0);
            c = __builtin_amdgcn_mfma_f32_16x16x32_bf16(ah, bm, c, 0, 0, 0);
            c = __builtin_amdgcn_mfma_f32_16x16x32_bf16(am, bh, c, 0, 0, 0);
            acc[n8] = c;
        }
    }

    // ---- phase B: K = 32..63, then bias ----
    {
        bf16x8 ah = *(const bf16x8*)(rowh + 32);
        bf16x8 am = *(const bf16x8*)(rowm + 32);
        #pragma unroll
        for (int n8 = 0; n8 < 8; ++n8) {
            int n = w4 * 8 + n8;
            bf16x8 bh = Bh[(n * 2 + 1) * 64 + l];
            bf16x8 bm = Bm[(n * 2 + 1) * 64 + l];
            f32x4 c = acc[n8];
            c = __builtin_amdgcn_mfma_f32_16x16x32_bf16(ah, bh, c, 0, 0, 0);
            c = __builtin_amdgcn_mfma_f32_16x16x32_bf16(ah, bm, c, 0, 0, 0);
            c = __builtin_amdgcn_mfma_f32_16x16x32_bf16(am, bh, c, 0, 0, 0);
            float bn = bfc[n * 16 + c16];
            c.x += bn; c.y += bn; c.z += bn; c.w += bn;
            acc[n8] = c;
        }
    }
#undef SPLIT

    // ---- softmax: row = g*4 + j; 16-lane reduce then 4-wave combine ----
    float m0 = -1e30f, m1 = -1e30f, m2 = -1e30f, m3 = -1e30f;
    #pragma unroll
    for (int n8 = 0; n8 < 8; ++n8) {
        m0 = fmaxf(m0, acc[n8].x); m1 = fmaxf(m1, acc[n8].y);
        m2 = fmaxf(m2, acc[n8].z); m3 = fmaxf(m3, acc[n8].w);
    }
    #pragma unroll
    for (int off = 8; off; off >>= 1) {
        m0 = fmaxf(m0, __shfl_xor(m0, off));
        m1 = fmaxf(m1, __shfl_xor(m1, off));
        m2 = fmaxf(m2, __shfl_xor(m2, off));
        m3 = fmaxf(m3, __shfl_xor(m3, off));
    }
    if (c16 == 0) {
        redmax[w4][g * 4 + 0] = m0;  redmax[w4][g * 4 + 1] = m1;
        redmax[w4][g * 4 + 2] = m2;  redmax[w4][g * 4 + 3] = m3;
    }
    __syncthreads();
#define GMAX(r) fmaxf(fmaxf(redmax[0][r], redmax[1][r]), \
                      fmaxf(redmax[2][r], redmax[3][r]))
    float g0 = GMAX(g * 4 + 0), g1 = GMAX(g * 4 + 1);
    float g2 = GMAX(g * 4 + 2), g3 = GMAX(g * 4 + 3);
#undef GMAX

    float s0 = 0.f, s1 = 0.f, s2 = 0.f, s3 = 0.f;
    #pragma unroll
    for (int n8 = 0; n8 < 8; ++n8) {
        acc[n8].x = __expf(acc[n8].x - g0); s0 += acc[n8].x;
        acc[n8].y = __expf(acc[n8].y - g1); s1 += acc[n8].y;
        acc[n8].z = __expf(acc[n8].z - g2); s2 += acc[n8].z;
        acc[n8].w = __expf(acc[n8].w - g3); s3 += acc[n8].w;
    }
    #pragma unroll
    for (int off = 8; off; off >>= 1) {
        s0 += __shfl_xor(s0, off); s1 += __shfl_xor(s1, off);
        s2 += __shfl_xor(s2, off); s3 += __shfl_xor(s3, off);
    }
    if (c16 == 0) {
        redsum[w4][g * 4 + 0] = s0;  redsum[w4][g * 4 + 1] = s1;
        redsum[w4][g * 4 + 2] = s2;  redsum[w4][g * 4 + 3] = s3;
    }
    __syncthreads();
#define GSUM(r) (redsum[0][r] + redsum[1][r] + redsum[2][r] + redsum[3][r])
    float i0 = 1.0f / GSUM(g * 4 + 0), i1 = 1.0f / GSUM(g * 4 + 1);
    float i2 = 1.0f / GSUM(g * 4 + 2), i3 = 1.0f / GSUM(g * 4 + 3);
#undef GSUM

    // ---- store: out[(vbase+g*4+j)*512 + n*16 + c16] ----
    #pragma unroll
    for (int n8 = 0; n8 < 8; ++n8) {
        int n = w4 * 8 + n8;
        float* op = out + (size_t)(vbase + g * 4) * 512 + n * 16 + c16;
        __builtin_nontemporal_store(acc[n8].x * i0, op);
        __builtin_nontemporal_store(acc[n8].y * i1, op + 512);
        __builtin_nontemporal_store(acc[n8].z * i2, op + 1024);
        __builtin_nontemporal_store(acc[n8].w * i3, op + 1536);
    }
}

extern "C" void kernel_launch(void* const* d_in, const int* in_sizes, int n_in,
                              void* d_out, int out_size, void* d_ws, size_t ws_size,
                              hipStream_t stream) {
    (void)n_in; (void)out_size; (void)ws_size;
    const float* vp  = (const float*)d_in[0];
    const int*   nb1 = (const int*)d_in[1];
    const int*   nb2 = (const int*)d_in[2];
    const float* wv1 = (const float*)d_in[3];
    const float* bv1 = (const float*)d_in[4];
    const float* w1  = (const float*)d_in[5];
    const float* b1  = (const float*)d_in[6];
    const float* wv2 = (const float*)d_in[7];
    const float* bv2 = (const float*)d_in[8];
    const float* w2  = (const float*)d_in[9];
    const float* b2  = (const float*)d_in[10];
    const float* wfc = (const float*)d_in[11];
    const float* bfc = (const float*)d_in[12];
    float* out = (float*)d_out;
    const int V = in_sizes[0];

    float* ws = (float*)d_ws;
    size_t off = 0;
    float* h    = ws + off; off += (size_t)V;
    float* h3   = ws + off; off += (size_t)V * 4;   // 16B aligned
    short* wBh  = (short*)(ws + off); off += 32768 / 2;   // 32768 shorts
    short* wBm  = (short*)(ws + off); off += 32768 / 2;
    short* wB2h = (short*)(ws + off); off += 6144 / 2;    // 6144 shorts
    short* wB2m = (short*)(ws + off); off += 6144 / 2;

    int nA = (V + 255) / 256;
    int nP = (32768 + 6144 + 255) / 256;
    kAP<<<nA + nP, 256, 0, stream>>>(vp, nb1, wv1, bv1, h,
                                     wfc, w2, wBh, wBm, wB2h, wB2m, V, nA);
    kB<<<(V + 255) / 256, 256, 0, stream>>>(h, h3, V);
    kF<<<V / 16, 256, 0, stream>>>(h3, nb2, w1, b1, wv2, bv2, b2,
                                   wBh, wBm, wB2h, wB2m, bfc, out, V);
}